// Round 1
// baseline (1834.364 us; speedup 1.0000x reference)
//
#include <hip/hip_runtime.h>
#include <cfloat>
#include <cmath>

// Shapes
#define T_ 16
#define R_ 200
#define W_ 50
#define FCWT 32
#define E_ 128
#define H_ 256
#define HG_ 256
#define NC_ 2
#define K_ 20
#define N_ 3200            // T_*R_

// ---------------- helpers ----------------
__device__ __forceinline__ void waveReduce2(float& a, float& b) {
#pragma unroll
    for (int o = 32; o > 0; o >>= 1) {
        a += __shfl_down(a, o, 64);
        b += __shfl_down(b, o, 64);
    }
}

// ---------------- K1: CWT magnitude ----------------
// scal[n][f][i] = |conv(x[n], wavelet_f)| ; pad left 24, right 25
__global__ __launch_bounds__(256) void cwt_kernel(const float* __restrict__ x,
                                                  const float* __restrict__ wr,
                                                  const float* __restrict__ wi,
                                                  float* __restrict__ scal) {
    int n = blockIdx.x, tid = threadIdx.x;
    __shared__ float sx[W_];
    __shared__ float swr[FCWT * W_];
    __shared__ float swi[FCWT * W_];
    if (tid < W_) sx[tid] = x[n * W_ + tid];
    for (int idx = tid; idx < FCWT * W_; idx += 256) { swr[idx] = wr[idx]; swi[idx] = wi[idx]; }
    __syncthreads();
    for (int idx = tid; idx < FCWT * W_; idx += 256) {
        int f = idx / W_, i = idx % W_;
        int jlo = (24 - i) > 0 ? (24 - i) : 0;
        int jhi = (73 - i) < 49 ? (73 - i) : 49;
        float re = 0.f, im = 0.f;
        for (int j = jlo; j <= jhi; ++j) {
            float xv = sx[i + j - 24];
            re += xv * swr[f * W_ + j];
            im += xv * swi[f * W_ + j];
        }
        scal[n * (FCWT * W_) + idx] = sqrtf(re * re + im * im);
    }
}

// ---------------- K2: conv1 (1->16, 3x3 pad1) stats pass ----------------
__global__ __launch_bounds__(256) void conv1_stats_kernel(const float* __restrict__ scal,
                                                          const float* __restrict__ w1,
                                                          const float* __restrict__ b1,
                                                          double* __restrict__ psum,
                                                          double* __restrict__ psq) {
    int n = blockIdx.x, tid = threadIdx.x;
    __shared__ float simg[34 * 52];
    __shared__ float sw[144];
    __shared__ float sa[4], sb[4];
    for (int idx = tid; idx < 34 * 52; idx += 256) {
        int yy = idx / 52, xx = idx % 52;
        float v = 0.f;
        if (yy >= 1 && yy <= 32 && xx >= 1 && xx <= 50)
            v = scal[n * 1600 + (yy - 1) * 50 + (xx - 1)];
        simg[idx] = v;
    }
    if (tid < 144) sw[tid] = w1[tid];
    __syncthreads();
    int lane = tid & 63, wid = tid >> 6;
    for (int c = 0; c < 16; ++c) {
        float w00 = sw[c * 9 + 0], w01 = sw[c * 9 + 1], w02 = sw[c * 9 + 2];
        float w10 = sw[c * 9 + 3], w11 = sw[c * 9 + 4], w12 = sw[c * 9 + 5];
        float w20 = sw[c * 9 + 6], w21 = sw[c * 9 + 7], w22 = sw[c * 9 + 8];
        float bias = b1[c];
        float s = 0.f, q = 0.f;
        for (int pos = tid; pos < 1600; pos += 256) {
            int y = pos / 50, xcol = pos % 50;
            const float* p = &simg[y * 52 + xcol];
            float acc = bias;
            acc += p[0] * w00 + p[1] * w01 + p[2] * w02;
            acc += p[52] * w10 + p[53] * w11 + p[54] * w12;
            acc += p[104] * w20 + p[105] * w21 + p[106] * w22;
            s += acc; q += acc * acc;
        }
        waveReduce2(s, q);
        if (lane == 0) { sa[wid] = s; sb[wid] = q; }
        __syncthreads();
        if (tid == 0) {
            float ss = sa[0] + sa[1] + sa[2] + sa[3];
            float qq = sb[0] + sb[1] + sb[2] + sb[3];
            psum[n * 16 + c] = (double)ss;
            psq[n * 16 + c] = (double)qq;
        }
        __syncthreads();
    }
}

// ---------------- K3: BN finalize (reduce partials -> scale/shift) ----------------
__global__ __launch_bounds__(256) void bn_finalize_kernel(const double* __restrict__ psum,
                                                          const double* __restrict__ psq,
                                                          const float* __restrict__ g,
                                                          const float* __restrict__ beta,
                                                          float* __restrict__ scale,
                                                          float* __restrict__ shift,
                                                          int C, double inv_count) {
    int c = blockIdx.x, tid = threadIdx.x;
    double s = 0.0, q = 0.0;
    for (int n = tid; n < N_; n += 256) { s += psum[n * C + c]; q += psq[n * C + c]; }
#pragma unroll
    for (int o = 32; o > 0; o >>= 1) { s += __shfl_down(s, o, 64); q += __shfl_down(q, o, 64); }
    __shared__ double sa[4], sb[4];
    int lane = tid & 63, wid = tid >> 6;
    if (lane == 0) { sa[wid] = s; sb[wid] = q; }
    __syncthreads();
    if (tid == 0) {
        s = sa[0] + sa[1] + sa[2] + sa[3];
        q = sb[0] + sb[1] + sb[2] + sb[3];
        double mu = s * inv_count;
        double var = q * inv_count - mu * mu;
        double rstd = 1.0 / sqrt(var + 1e-5);
        double gg = (double)g[c];
        scale[c] = (float)(gg * rstd);
        shift[c] = (float)((double)beta[c] - mu * rstd * gg);
    }
}

// ---------------- K4: conv1 recompute + norm + relu + pool 2x2 ----------------
__global__ __launch_bounds__(256) void conv1_norm_pool_kernel(const float* __restrict__ scal,
                                                              const float* __restrict__ w1,
                                                              const float* __restrict__ b1,
                                                              const float* __restrict__ scale,
                                                              const float* __restrict__ shift,
                                                              float* __restrict__ pooled1) {
    int n = blockIdx.x, tid = threadIdx.x;
    __shared__ float simg[34 * 52];
    __shared__ float sw[144];
    __shared__ float sbias[16], ssc[16], ssh[16];
    for (int idx = tid; idx < 34 * 52; idx += 256) {
        int yy = idx / 52, xx = idx % 52;
        float v = 0.f;
        if (yy >= 1 && yy <= 32 && xx >= 1 && xx <= 50)
            v = scal[n * 1600 + (yy - 1) * 50 + (xx - 1)];
        simg[idx] = v;
    }
    if (tid < 144) sw[tid] = w1[tid];
    if (tid < 16) { sbias[tid] = b1[tid]; ssc[tid] = scale[tid]; ssh[tid] = shift[tid]; }
    __syncthreads();
    for (int idx = tid; idx < 16 * 16 * 25; idx += 256) {
        int c = idx / 400, rem = idx % 400, py = rem / 25, px = rem % 25;
        int y0 = py * 2, x0 = px * 2;
        const float* wc = &sw[c * 9];
        float bias = sbias[c], sc = ssc[c], sh = ssh[c];
        float m = -FLT_MAX;
#pragma unroll
        for (int dy = 0; dy < 2; ++dy)
#pragma unroll
            for (int dx = 0; dx < 2; ++dx) {
                const float* p = &simg[(y0 + dy) * 52 + (x0 + dx)];
                float acc = bias;
                acc += p[0] * wc[0] + p[1] * wc[1] + p[2] * wc[2];
                acc += p[52] * wc[3] + p[53] * wc[4] + p[54] * wc[5];
                acc += p[104] * wc[6] + p[105] * wc[7] + p[106] * wc[8];
                acc = acc * sc + sh;
                m = fmaxf(m, acc);
            }
        pooled1[((n * 16 + c) * 16 + py) * 25 + px] = fmaxf(m, 0.f);
    }
}

// ---------------- K5: conv2 (16->32, 3x3 pad1) stats pass (recompute, no store) ----------------
__global__ __launch_bounds__(256) void conv2_stats_kernel(const float* __restrict__ pooled1,
                                                          const float* __restrict__ w2,
                                                          const float* __restrict__ b2,
                                                          double* __restrict__ psum,
                                                          double* __restrict__ psq) {
    int n = blockIdx.x, tid = threadIdx.x;
    __shared__ float simg[16 * 18 * 27];
    __shared__ float swT[144 * 32];  // [ (ci*3+ky)*3+kx ][ co ]
    __shared__ float ls[256], lq[256];
    for (int idx = tid; idx < 16 * 18 * 27; idx += 256) {
        int ci = idx / (18 * 27), rem = idx % (18 * 27), yy = rem / 27, xx = rem % 27;
        float v = 0.f;
        if (yy >= 1 && yy <= 16 && xx >= 1 && xx <= 25)
            v = pooled1[((n * 16 + ci) * 16 + (yy - 1)) * 25 + (xx - 1)];
        simg[idx] = v;
    }
    for (int idx = tid; idx < 4608; idx += 256) {
        int co = idx / 144, r = idx % 144;
        swT[r * 32 + co] = w2[idx];
    }
    __syncthreads();
    int co = tid & 31, pg = tid >> 5;   // 8 threads per co
    float bias = b2[co];
    float s = 0.f, q = 0.f;
    for (int k = 0; k < 10; ++k) {
        int task = pg + 8 * k;           // 0..79 : y = task/5, xseg = task%5
        int y = task / 5, xs = (task % 5) * 5;
        float a0 = bias, a1 = bias, a2 = bias, a3 = bias, a4 = bias;
        for (int ci = 0; ci < 16; ++ci) {
            const float* base = &simg[ci * 486];
#pragma unroll
            for (int ky = 0; ky < 3; ++ky) {
                const float* row = &base[(y + ky) * 27 + xs];
                float i0 = row[0], i1 = row[1], i2 = row[2], i3 = row[3];
                float i4 = row[4], i5 = row[5], i6 = row[6];
                const float* wp = &swT[((ci * 3 + ky) * 3) * 32 + co];
                float w0 = wp[0], w1 = wp[32], w2v = wp[64];
                a0 += i0 * w0 + i1 * w1 + i2 * w2v;
                a1 += i1 * w0 + i2 * w1 + i3 * w2v;
                a2 += i2 * w0 + i3 * w1 + i4 * w2v;
                a3 += i3 * w0 + i4 * w1 + i5 * w2v;
                a4 += i4 * w0 + i5 * w1 + i6 * w2v;
            }
        }
        s += a0 + a1 + a2 + a3 + a4;
        q += a0 * a0 + a1 * a1 + a2 * a2 + a3 * a3 + a4 * a4;
    }
    ls[tid] = s; lq[tid] = q;
    __syncthreads();
    if (tid < 32) {
        for (int j = 1; j < 8; ++j) { s += ls[tid + 32 * j]; q += lq[tid + 32 * j]; }
        psum[n * 32 + tid] = (double)s;
        psq[n * 32 + tid] = (double)q;
    }
}

// ---------------- K6: conv2 recompute + norm + relu + pool (VALID -> 8x12) ----------------
__global__ __launch_bounds__(256) void conv2_norm_pool_kernel(const float* __restrict__ pooled1,
                                                              const float* __restrict__ w2,
                                                              const float* __restrict__ b2,
                                                              const float* __restrict__ scale,
                                                              const float* __restrict__ shift,
                                                              float* __restrict__ pooled2) {
    int n = blockIdx.x, tid = threadIdx.x;
    __shared__ float simg[16 * 18 * 27];
    __shared__ float sw[4608];
    __shared__ float sbias[32], ssc[32], ssh[32];
    for (int idx = tid; idx < 16 * 18 * 27; idx += 256) {
        int ci = idx / (18 * 27), rem = idx % (18 * 27), yy = rem / 27, xx = rem % 27;
        float v = 0.f;
        if (yy >= 1 && yy <= 16 && xx >= 1 && xx <= 25)
            v = pooled1[((n * 16 + ci) * 16 + (yy - 1)) * 25 + (xx - 1)];
        simg[idx] = v;
    }
    for (int idx = tid; idx < 4608; idx += 256) sw[idx] = w2[idx];
    if (tid < 32) { sbias[tid] = b2[tid]; ssc[tid] = scale[tid]; ssh[tid] = shift[tid]; }
    __syncthreads();
    for (int idx = tid; idx < 32 * 8 * 12; idx += 256) {
        int co = idx / 96, rem = idx % 96, py = rem / 12, px = rem % 12;
        int y0 = 2 * py, x0 = 2 * px;
        float bias = sbias[co], sc = ssc[co], sh = ssh[co];
        const float* wc = &sw[co * 144];
        float m = -FLT_MAX;
#pragma unroll
        for (int dy = 0; dy < 2; ++dy)
#pragma unroll
            for (int dx = 0; dx < 2; ++dx) {
                float acc = bias;
                for (int ci = 0; ci < 16; ++ci) {
                    const float* p = &simg[ci * 486 + (y0 + dy) * 27 + (x0 + dx)];
                    const float* w = &wc[ci * 9];
                    acc += p[0] * w[0] + p[1] * w[1] + p[2] * w[2];
                    acc += p[27] * w[3] + p[28] * w[4] + p[29] * w[5];
                    acc += p[54] * w[6] + p[55] * w[7] + p[56] * w[8];
                }
                acc = acc * sc + sh;
                m = fmaxf(m, acc);
            }
        pooled2[((n * 32 + co) * 8 + py) * 12 + px] = fmaxf(m, 0.f);
    }
}

// ---------------- K7: channel mean over 8x12 ----------------
__global__ __launch_bounds__(256) void chan_mean_kernel(const float* __restrict__ pooled2,
                                                        float* __restrict__ pm) {
    int gid = blockIdx.x * 256 + threadIdx.x;
    if (gid < N_ * 32) {
        const float* p = pooled2 + (size_t)gid * 96;
        float s = 0.f;
        for (int i = 0; i < 96; ++i) s += p[i];
        pm[gid] = s * (1.f / 96.f);
    }
}

// ---------------- K8: FC 32->128 ----------------
__global__ __launch_bounds__(128) void fc_kernel(const float* __restrict__ pm,
                                                 const float* __restrict__ fc_w,
                                                 const float* __restrict__ fc_b,
                                                 float* __restrict__ emb) {
    int n = blockIdx.x, e = threadIdx.x;
    __shared__ float sp[32];
    if (e < 32) sp[e] = pm[n * 32 + e];
    __syncthreads();
    const float* w = fc_w + e * 32;
    float acc = fc_b[e];
    for (int c = 0; c < 32; ++c) acc += sp[c] * w[c];
    emb[n * 128 + e] = acc;
}

// ---------------- K9: Q/K projections 128->128 ----------------
__global__ __launch_bounds__(128) void qk_kernel(const float* __restrict__ emb,
                                                 const float* __restrict__ q_w,
                                                 const float* __restrict__ q_b,
                                                 const float* __restrict__ k_w,
                                                 const float* __restrict__ k_b,
                                                 float* __restrict__ Q,
                                                 float* __restrict__ Kp) {
    int n = blockIdx.x, e = threadIdx.x;
    const float* w = (blockIdx.y == 0) ? q_w : k_w;
    const float* b = (blockIdx.y == 0) ? q_b : k_b;
    float* out = (blockIdx.y == 0) ? Q : Kp;
    __shared__ float se[128];
    se[e] = emb[n * 128 + e];
    __syncthreads();
    const float* wr = w + e * 128;
    float acc = b[e];
    for (int k = 0; k < 128; ++k) acc += se[k] * wr[k];
    out[n * 128 + e] = acc;
}

// ---------------- K10: attention scores + leaky relu ----------------
__global__ __launch_bounds__(256) void attn_kernel(const float* __restrict__ Q,
                                                   const float* __restrict__ Kp,
                                                   float* __restrict__ attn) {
    int r = blockIdx.x, t = blockIdx.y, tid = threadIdx.x;
    __shared__ float sq[128];
    if (tid < 128) sq[tid] = Q[(t * 200 + r) * 128 + tid];
    __syncthreads();
    if (tid < 200) {
        const float4* kp4 = (const float4*)(Kp + (size_t)(t * 200 + tid) * 128);
        float acc = 0.f;
#pragma unroll 8
        for (int e4 = 0; e4 < 32; ++e4) {
            float4 k4 = kp4[e4];
            acc += sq[e4 * 4 + 0] * k4.x + sq[e4 * 4 + 1] * k4.y +
                   sq[e4 * 4 + 2] * k4.z + sq[e4 * 4 + 3] * k4.w;
        }
        acc = acc / 11.313708498984761f;
        acc = (acc >= 0.f) ? acc : 0.2f * acc;
        attn[(size_t)(t * 200 + r) * 200 + tid] = acc;
    }
}

// ---------------- K11: top-k(20) mask + softmax -> adj ----------------
__global__ __launch_bounds__(64) void topk_softmax_kernel(const float* __restrict__ attn,
                                                          float* __restrict__ adj) {
    int row = blockIdx.x;     // t*200 + r
    int lane = threadIdx.x;   // 64 threads
    const float* a = attn + (size_t)row * 200;
    float v[4], w[4];
#pragma unroll
    for (int j = 0; j < 4; ++j) {
        int i = lane + 64 * j;
        float x = (i < 200) ? a[i] : -FLT_MAX;
        v[j] = x; w[j] = x;
    }
    unsigned sel = 0;
    for (int it = 0; it < K_; ++it) {
        float best = -FLT_MAX; int bidx = 0x7fffffff;
#pragma unroll
        for (int j = 0; j < 4; ++j) {
            int i = lane + 64 * j;
            if (w[j] > best || (w[j] == best && i < bidx)) { best = w[j]; bidx = i; }
        }
#pragma unroll
        for (int off = 32; off > 0; off >>= 1) {
            float ob = __shfl_down(best, off, 64);
            int oi = __shfl_down(bidx, off, 64);
            if (ob > best || (ob == best && oi < bidx)) { best = ob; bidx = oi; }
        }
        bidx = __shfl(bidx, 0, 64);
        if ((bidx & 63) == lane) { int j = bidx >> 6; w[j] = -FLT_MAX; sel |= (1u << j); }
    }
    float mv[4]; float m = -FLT_MAX;
#pragma unroll
    for (int j = 0; j < 4; ++j) {
        int i = lane + 64 * j;
        float x = -1e9f;
        if (i < 200 && ((sel >> j) & 1u)) x = (v[j] == 0.f) ? -1e9f : v[j];
        mv[j] = x; m = fmaxf(m, x);
    }
#pragma unroll
    for (int off = 32; off > 0; off >>= 1) m = fmaxf(m, __shfl_xor(m, off, 64));
    float s = 0.f; float e[4];
#pragma unroll
    for (int j = 0; j < 4; ++j) {
        int i = lane + 64 * j;
        e[j] = (i < 200) ? expf(mv[j] - m) : 0.f;
        s += e[j];
    }
#pragma unroll
    for (int off = 32; off > 0; off >>= 1) s += __shfl_xor(s, off, 64);
    float inv = 1.f / s;
#pragma unroll
    for (int j = 0; j < 4; ++j) {
        int i = lane + 64 * j;
        if (i < 200) adj[(size_t)row * 200 + i] = e[j] * inv;
    }
}

// ---------------- K12: build normalized adjacency An ----------------
// adj_sl = adj with diag: (diag==0 ? 1 : diag); Bm = adj_sl^T ; deg=rowsum(Bm);
// An[r][s] = dinv[r]*adj_sl[s][r]*dinv[s]
__global__ __launch_bounds__(256) void build_An_kernel(const float* __restrict__ adj,
                                                       float* __restrict__ An) {
    int t = blockIdx.x, tid = threadIdx.x;
    __shared__ float dinv[200];
    if (tid < 200) {
        float acc = 0.f;
        for (int s = 0; s < 200; ++s) {
            float v = adj[(size_t)(t * 200 + s) * 200 + tid];
            if (s == tid) v = (v == 0.f) ? 1.f : v;
            acc += v;
        }
        float d = (acc > 0.f) ? acc : 1.f;
        dinv[tid] = 1.f / sqrtf(d);
    }
    __syncthreads();
    for (int idx = tid; idx < 200 * 200; idx += 256) {
        int r = idx / 200, s = idx % 200;
        float v = adj[(size_t)(t * 200 + s) * 200 + r];
        if (s == r) v = (v == 0.f) ? 1.f : v;
        An[(size_t)(t * 200 + r) * 200 + s] = dinv[r] * v * dinv[s];
    }
}

// ---------------- K13: row @ weight (IN -> 256), no bias ----------------
__global__ __launch_bounds__(256) void linear_kernel(const float* __restrict__ in,
                                                     const float* __restrict__ w,
                                                     float* __restrict__ out, int IN) {
    int n = blockIdx.x, h = threadIdx.x;
    __shared__ float s[256];
    for (int i = h; i < IN; i += 256) s[i] = in[n * IN + i];
    __syncthreads();
    float acc = 0.f;
    for (int k = 0; k < IN; ++k) acc += s[k] * w[k * 256 + h];
    out[(size_t)n * 256 + h] = acc;
}

// ---------------- K14: GCN aggregation: relu(An @ X + b) ----------------
__global__ __launch_bounds__(256) void gcn_agg_kernel(const float* __restrict__ An,
                                                      const float* __restrict__ X,
                                                      const float* __restrict__ b,
                                                      float* __restrict__ out) {
    int r = blockIdx.x, t = blockIdx.y, h = threadIdx.x;
    __shared__ float sa[200];
    for (int i = h; i < 200; i += 256) sa[i] = An[(size_t)(t * 200 + r) * 200 + i];
    __syncthreads();
    const float* Xt = X + (size_t)t * 200 * 256;
    float acc = 0.f;
    for (int s = 0; s < 200; ++s) acc += sa[s] * Xt[s * 256 + h];
    out[(size_t)(t * 200 + r) * 256 + h] = fmaxf(acc + b[h], 0.f);
}

// ---------------- K15: mean over R ----------------
__global__ __launch_bounds__(256) void gemb_kernel(const float* __restrict__ g2,
                                                   float* __restrict__ g_emb) {
    int t = blockIdx.x, h = threadIdx.x;
    float acc = 0.f;
    for (int r = 0; r < 200; ++r) acc += g2[(size_t)(t * 200 + r) * 256 + h];
    g_emb[t * 256 + h] = acc * (1.f / 200.f);
}

// ---------------- K16: GRU input-side matvecs GI[t][0..767] ----------------
__global__ __launch_bounds__(256) void gi_kernel(const float* __restrict__ g_emb,
                                                 const float* __restrict__ wih,
                                                 const float* __restrict__ bih,
                                                 float* __restrict__ GI) {
    int t = blockIdx.x, tid = threadIdx.x;
    __shared__ float sg[256];
    sg[tid] = g_emb[t * 256 + tid];
    __syncthreads();
    for (int j = tid; j < 768; j += 256) {
        const float* w = wih + j * 256;
        float acc = bih[j];
        for (int k = 0; k < 256; ++k) acc += sg[k] * w[k];
        GI[t * 768 + j] = acc;
    }
}

// ---------------- K17: sequential GRU + classifier (single block) ----------------
__global__ __launch_bounds__(256) void gru_cls_kernel(const float* __restrict__ GI,
                                                      const float* __restrict__ whh,
                                                      const float* __restrict__ bhh,
                                                      const float* __restrict__ cls_w,
                                                      const float* __restrict__ cls_b,
                                                      float* __restrict__ out) {
    int tid = threadIdx.x;
    __shared__ float sh[256];
    __shared__ float s0[4], s1[4];
    sh[tid] = 0.f;
    __syncthreads();
    const float* w0 = whh + (size_t)tid * 256;
    const float* w1 = whh + (size_t)(256 + tid) * 256;
    const float* w2 = whh + (size_t)(512 + tid) * 256;
    float b0 = bhh[tid], b1 = bhh[256 + tid], b2 = bhh[512 + tid];
    for (int t = 0; t < 16; ++t) {
        float hr = b0, hz = b1, hn = b2;
        for (int k = 0; k < 256; ++k) {
            float hv = sh[k];
            hr += hv * w0[k];
            hz += hv * w1[k];
            hn += hv * w2[k];
        }
        float ir = GI[t * 768 + tid];
        float iz = GI[t * 768 + 256 + tid];
        float inn = GI[t * 768 + 512 + tid];
        float r = 1.f / (1.f + expf(-(ir + hr)));
        float z = 1.f / (1.f + expf(-(iz + hz)));
        float nn = tanhf(inn + r * hn);
        float hnew = (1.f - z) * nn + z * sh[tid];
        __syncthreads();
        sh[tid] = hnew;
        __syncthreads();
    }
    float v0 = sh[tid] * cls_w[tid];
    float v1 = sh[tid] * cls_w[256 + tid];
    waveReduce2(v0, v1);
    int lane = tid & 63, wid = tid >> 6;
    if (lane == 0) { s0[wid] = v0; s1[wid] = v1; }
    __syncthreads();
    if (tid == 0) {
        out[0] = s0[0] + s0[1] + s0[2] + s0[3] + cls_b[0];
        out[1] = s1[0] + s1[1] + s1[2] + s1[3] + cls_b[1];
    }
}

// ---------------- K18: avg_adj + edge variance ----------------
__global__ __launch_bounds__(256) void edge_kernel(const float* __restrict__ adj,
                                                   float* __restrict__ out) {
    int gid = blockIdx.x * 256 + threadIdx.x;
    float var = 0.f;
    if (gid < 40000) {
        float v[16]; float s = 0.f;
#pragma unroll
        for (int t = 0; t < 16; ++t) { v[t] = adj[t * 40000 + gid]; s += v[t]; }
        float mean = s * (1.f / 16.f);
        float q = 0.f;
#pragma unroll
        for (int t = 0; t < 16; ++t) { float d = v[t] - mean; q += d * d; }
        var = q * (1.f / 15.f);
        out[2 + gid] = mean;
    }
    float dummy = 0.f;
    waveReduce2(var, dummy);
    __shared__ float sa[4];
    int lane = threadIdx.x & 63, wid = threadIdx.x >> 6;
    if (lane == 0) sa[wid] = var;
    __syncthreads();
    if (threadIdx.x == 0) {
        float bs = sa[0] + sa[1] + sa[2] + sa[3];
        atomicAdd(&out[40002], bs * (1.f / 40000.f));
    }
}

// ---------------- host ----------------
extern "C" void kernel_launch(void* const* d_in, const int* in_sizes, int n_in,
                              void* d_out, int out_size, void* d_ws, size_t ws_size,
                              hipStream_t stream) {
    const float* tw      = (const float*)d_in[0];
    const float* wav_r   = (const float*)d_in[1];
    const float* wav_i   = (const float*)d_in[2];
    const float* conv1_w = (const float*)d_in[3];
    const float* conv1_b = (const float*)d_in[4];
    const float* bn1_g   = (const float*)d_in[5];
    const float* bn1_b   = (const float*)d_in[6];
    const float* conv2_w = (const float*)d_in[7];
    const float* conv2_b = (const float*)d_in[8];
    const float* bn2_g   = (const float*)d_in[9];
    const float* bn2_b   = (const float*)d_in[10];
    const float* fc_w    = (const float*)d_in[11];
    const float* fc_b    = (const float*)d_in[12];
    const float* q_w     = (const float*)d_in[13];
    const float* q_b     = (const float*)d_in[14];
    const float* k_w     = (const float*)d_in[15];
    const float* k_b     = (const float*)d_in[16];
    const float* gcn1_w  = (const float*)d_in[17];
    const float* gcn1_b  = (const float*)d_in[18];
    const float* gcn2_w  = (const float*)d_in[19];
    const float* gcn2_b  = (const float*)d_in[20];
    const float* gru_wih = (const float*)d_in[21];
    const float* gru_whh = (const float*)d_in[22];
    const float* gru_bih = (const float*)d_in[23];
    const float* gru_bhh = (const float*)d_in[24];
    const float* cls_w   = (const float*)d_in[25];
    const float* cls_b   = (const float*)d_in[26];
    float* out = (float*)d_out;

    // workspace carve-up
    size_t off = 0;
    char* Wb = (char*)d_ws;
    auto take = [&](size_t bytes) -> char* {
        char* p = Wb + off;
        off += (bytes + 255) & ~(size_t)255;
        return p;
    };
    float* pooled1 = (float*)take((size_t)N_ * 16 * 16 * 25 * 4);   // 81.92 MB
    // union region: scal (N*32*50) lives here until conv1 done; pooled2 (N*32*8*12) after
    char* uni = take((size_t)N_ * 32 * 8 * 12 * 4);                  // 39.32 MB
    float* scal = (float*)uni;
    float* pooled2 = (float*)uni;
    double* p1sum = (double*)take((size_t)N_ * 16 * 8);
    double* p1sq  = (double*)take((size_t)N_ * 16 * 8);
    double* p2sum = (double*)take((size_t)N_ * 32 * 8);
    double* p2sq  = (double*)take((size_t)N_ * 32 * 8);
    float* scale1 = (float*)take(16 * 4);
    float* shift1 = (float*)take(16 * 4);
    float* scale2 = (float*)take(32 * 4);
    float* shift2 = (float*)take(32 * 4);
    float* pm   = (float*)take((size_t)N_ * 32 * 4);
    float* emb  = (float*)take((size_t)N_ * 128 * 4);
    float* Q    = (float*)take((size_t)N_ * 128 * 4);
    float* Kp   = (float*)take((size_t)N_ * 128 * 4);
    float* attn = (float*)take((size_t)T_ * 200 * 200 * 4);
    float* adj  = (float*)take((size_t)T_ * 200 * 200 * 4);
    float* An   = (float*)take((size_t)T_ * 200 * 200 * 4);
    float* X1   = (float*)take((size_t)N_ * 256 * 4);
    float* g1   = (float*)take((size_t)N_ * 256 * 4);
    float* X2   = (float*)take((size_t)N_ * 256 * 4);
    float* g2   = (float*)take((size_t)N_ * 256 * 4);
    float* g_emb = (float*)take((size_t)T_ * 256 * 4);
    float* GI   = (float*)take((size_t)T_ * 768 * 4);
    (void)ws_size; (void)in_sizes; (void)n_in; (void)out_size;

    // 1) CWT
    cwt_kernel<<<N_, 256, 0, stream>>>(tw, wav_r, wav_i, scal);
    // 2) conv1 stats -> BN1 -> norm+pool
    conv1_stats_kernel<<<N_, 256, 0, stream>>>(scal, conv1_w, conv1_b, p1sum, p1sq);
    bn_finalize_kernel<<<16, 256, 0, stream>>>(p1sum, p1sq, bn1_g, bn1_b, scale1, shift1,
                                               16, 1.0 / 5120000.0);
    conv1_norm_pool_kernel<<<N_, 256, 0, stream>>>(scal, conv1_w, conv1_b, scale1, shift1,
                                                   pooled1);
    // 3) conv2 stats -> BN2 -> norm+pool (pooled2 aliases scal region; scal is dead now)
    conv2_stats_kernel<<<N_, 256, 0, stream>>>(pooled1, conv2_w, conv2_b, p2sum, p2sq);
    bn_finalize_kernel<<<32, 256, 0, stream>>>(p2sum, p2sq, bn2_g, bn2_b, scale2, shift2,
                                               32, 1.0 / 1280000.0);
    conv2_norm_pool_kernel<<<N_, 256, 0, stream>>>(pooled1, conv2_w, conv2_b, scale2, shift2,
                                                   pooled2);
    // 4) pooled mean + FC + Q/K
    chan_mean_kernel<<<(N_ * 32 + 255) / 256, 256, 0, stream>>>(pooled2, pm);
    fc_kernel<<<N_, 128, 0, stream>>>(pm, fc_w, fc_b, emb);
    qk_kernel<<<dim3(N_, 2), 128, 0, stream>>>(emb, q_w, q_b, k_w, k_b, Q, Kp);
    // 5) attention -> topk softmax -> An
    attn_kernel<<<dim3(200, 16), 256, 0, stream>>>(Q, Kp, attn);
    topk_softmax_kernel<<<N_, 64, 0, stream>>>(attn, adj);
    build_An_kernel<<<16, 256, 0, stream>>>(adj, An);
    // 6) GCN x2
    linear_kernel<<<N_, 256, 0, stream>>>(emb, gcn1_w, X1, 128);
    gcn_agg_kernel<<<dim3(200, 16), 256, 0, stream>>>(An, X1, gcn1_b, g1);
    linear_kernel<<<N_, 256, 0, stream>>>(g1, gcn2_w, X2, 256);
    gcn_agg_kernel<<<dim3(200, 16), 256, 0, stream>>>(An, X2, gcn2_b, g2);
    // 7) graph embedding + GRU + classifier
    gemb_kernel<<<16, 256, 0, stream>>>(g2, g_emb);
    gi_kernel<<<16, 256, 0, stream>>>(g_emb, gru_wih, gru_bih, GI);
    gru_cls_kernel<<<1, 256, 0, stream>>>(GI, gru_whh, gru_bhh, cls_w, cls_b, out);
    // 8) avg_adj + edge_var
    hipMemsetAsync(out + 40002, 0, sizeof(float), stream);
    edge_kernel<<<(40000 + 255) / 256, 256, 0, stream>>>(adj, out);
}

// Round 2
// 903.039 us; speedup vs baseline: 2.0313x; 2.0313x over previous
//
#include <hip/hip_runtime.h>
#include <cfloat>
#include <cmath>

// Shapes
#define T_ 16
#define R_ 200
#define W_ 50
#define FCWT 32
#define E_ 128
#define K_ 20
#define N_ 3200            // T_*R_

// ---------------- helpers ----------------
__device__ __forceinline__ void waveReduce2(float& a, float& b) {
#pragma unroll
    for (int o = 32; o > 0; o >>= 1) {
        a += __shfl_down(a, o, 64);
        b += __shfl_down(b, o, 64);
    }
}

// ---------------- K1: CWT magnitude + conv1 BN stats (fused) ----------------
// scal[n][f][i] = |conv(x[n], wavelet_f)|, then conv1 (1->16, 3x3 pad1) stats
// computed from the LDS-resident padded image.
__global__ __launch_bounds__(256) void cwt_conv1_stats_kernel(const float* __restrict__ x,
                                                              const float* __restrict__ wr,
                                                              const float* __restrict__ wi,
                                                              const float* __restrict__ w1,
                                                              const float* __restrict__ b1,
                                                              float* __restrict__ scal,
                                                              double* __restrict__ psum,
                                                              double* __restrict__ psq) {
    int n = blockIdx.x, tid = threadIdx.x;
    __shared__ float sx[W_];
    __shared__ float swr[FCWT * W_];
    __shared__ float swi[FCWT * W_];
    __shared__ float P1[34 * 52];            // padded scal image (rows=freq, cols=time)
    __shared__ float ls[256], lq[256];
    if (tid < W_) sx[tid] = x[n * W_ + tid];
    for (int idx = tid; idx < FCWT * W_; idx += 256) { swr[idx] = wr[idx]; swi[idx] = wi[idx]; }
    for (int idx = tid; idx < 34 * 52; idx += 256) P1[idx] = 0.f;
    __syncthreads();
    for (int idx = tid; idx < 1600; idx += 256) {
        int f = idx / 50, i = idx % 50;
        int jlo = (24 - i) > 0 ? (24 - i) : 0;
        int jhi = (73 - i) < 49 ? (73 - i) : 49;
        float re = 0.f, im = 0.f;
        for (int j = jlo; j <= jhi; ++j) {
            float xv = sx[i + j - 24];
            re += xv * swr[f * 50 + j];
            im += xv * swi[f * 50 + j];
        }
        float v = sqrtf(re * re + im * im);
        scal[n * 1600 + idx] = v;
        P1[(f + 1) * 52 + (i + 1)] = v;
    }
    __syncthreads();
    // conv1 stats: thread owns channel c = tid&15, 9 weights in registers
    int c = tid & 15, pgq = tid >> 4;
    float wv[9];
#pragma unroll
    for (int j = 0; j < 9; ++j) wv[j] = w1[c * 9 + j];
    float bias = b1[c];
    float s = 0.f, q = 0.f;
    for (int k = 0; k < 100; ++k) {
        int pos = pgq + 16 * k;               // 0..1599
        int y = pos / 50, xx = pos % 50;
        const float* p = &P1[y * 52 + xx];
        float v = bias + p[0] * wv[0] + p[1] * wv[1] + p[2] * wv[2]
                       + p[52] * wv[3] + p[53] * wv[4] + p[54] * wv[5]
                       + p[104] * wv[6] + p[105] * wv[7] + p[106] * wv[8];
        s += v; q += v * v;
    }
    ls[tid] = s; lq[tid] = q;
    __syncthreads();
    if (tid < 16) {
        float ss = 0.f, qq = 0.f;
        for (int g = 0; g < 16; ++g) { ss += ls[tid + 16 * g]; qq += lq[tid + 16 * g]; }
        psum[n * 16 + tid] = (double)ss;
        psq[n * 16 + tid] = (double)qq;
    }
}

// ---------------- K2: BN finalize (reduce partials -> scale/shift) ----------------
__global__ __launch_bounds__(256) void bn_finalize_kernel(const double* __restrict__ psum,
                                                          const double* __restrict__ psq,
                                                          const float* __restrict__ g,
                                                          const float* __restrict__ beta,
                                                          float* __restrict__ scale,
                                                          float* __restrict__ shift,
                                                          int C, double inv_count) {
    int c = blockIdx.x, tid = threadIdx.x;
    double s = 0.0, q = 0.0;
    for (int n = tid; n < N_; n += 256) { s += psum[n * C + c]; q += psq[n * C + c]; }
#pragma unroll
    for (int o = 32; o > 0; o >>= 1) { s += __shfl_down(s, o, 64); q += __shfl_down(q, o, 64); }
    __shared__ double sa[4], sb[4];
    int lane = tid & 63, wid = tid >> 6;
    if (lane == 0) { sa[wid] = s; sb[wid] = q; }
    __syncthreads();
    if (tid == 0) {
        s = sa[0] + sa[1] + sa[2] + sa[3];
        q = sb[0] + sb[1] + sb[2] + sb[3];
        double mu = s * inv_count;
        double var = q * inv_count - mu * mu;
        double rstd = 1.0 / sqrt(var + 1e-5);
        double gg = (double)g[c];
        scale[c] = (float)(gg * rstd);
        shift[c] = (float)((double)beta[c] - mu * rstd * gg);
    }
}

// ---------------- K3: conv1 recompute + norm + relu + pool 2x2 ----------------
// thread owns channel c = tid>>4, weights in registers, 25 pooled cells each
__global__ __launch_bounds__(256) void conv1_norm_pool_kernel(const float* __restrict__ scal,
                                                              const float* __restrict__ w1,
                                                              const float* __restrict__ b1,
                                                              const float* __restrict__ scale,
                                                              const float* __restrict__ shift,
                                                              float* __restrict__ pooled1) {
    int n = blockIdx.x, tid = threadIdx.x;
    __shared__ float P1[34 * 52];
    for (int idx = tid; idx < 34 * 52; idx += 256) {
        int yy = idx / 52, xx = idx % 52;
        float v = 0.f;
        if (yy >= 1 && yy <= 32 && xx >= 1 && xx <= 50)
            v = scal[n * 1600 + (yy - 1) * 50 + (xx - 1)];
        P1[idx] = v;
    }
    __syncthreads();
    int c = tid >> 4, sub = tid & 15;
    float wv[9];
#pragma unroll
    for (int j = 0; j < 9; ++j) wv[j] = w1[c * 9 + j];
    float bias = b1[c], sc = scale[c], sh = shift[c];
    for (int k = 0; k < 25; ++k) {
        int cell = sub + 16 * k;              // 0..399
        int py = cell / 25, px = cell % 25;
        int y0 = 2 * py, x0 = 2 * px;
        float p[4][4];
#pragma unroll
        for (int iy = 0; iy < 4; ++iy)
#pragma unroll
            for (int ix = 0; ix < 4; ++ix)
                p[iy][ix] = P1[(y0 + iy) * 52 + x0 + ix];
        float m = -FLT_MAX;
#pragma unroll
        for (int dy = 0; dy < 2; ++dy)
#pragma unroll
            for (int dx = 0; dx < 2; ++dx) {
                float acc = bias;
#pragma unroll
                for (int ky = 0; ky < 3; ++ky)
#pragma unroll
                    for (int kx = 0; kx < 3; ++kx)
                        acc += p[dy + ky][dx + kx] * wv[ky * 3 + kx];
                m = fmaxf(m, acc * sc + sh);
            }
        pooled1[((n * 16 + c) * 16 + py) * 25 + px] = fmaxf(m, 0.f);
    }
}

// ---------------- K4: conv2 single pass: conv + stats + pooled max/min ----------------
// register-blocked 2 rows x 6 cols; stores per-2x2-window max (and min) in
// mm[(n*96+cell)*stride + co] layout (coalesced over co).
__global__ __launch_bounds__(256) void conv2_compute_kernel(const float* __restrict__ pooled1,
                                                            const float* __restrict__ w2,
                                                            const float* __restrict__ b2,
                                                            float* __restrict__ mm,
                                                            double* __restrict__ psum,
                                                            double* __restrict__ psq,
                                                            int store_min) {
    int n = blockIdx.x, tid = threadIdx.x;
    __shared__ float P2[16 * 18 * 27];
    __shared__ float swT[144 * 32];           // [(ci*3+ky)*3+kx][co]
    __shared__ float ls[256], lq[256];
    for (int idx = tid; idx < 16 * 18 * 27; idx += 256) {
        int ci = idx / 486, rem = idx % 486, yy = rem / 27, xx = rem % 27;
        float v = 0.f;
        if (yy >= 1 && yy <= 16 && xx >= 1 && xx <= 25)
            v = pooled1[((n * 16 + ci) * 16 + (yy - 1)) * 25 + (xx - 1)];
        P2[idx] = v;
    }
    for (int idx = tid; idx < 4608; idx += 256) {
        int co = idx / 144, r = idx % 144;
        swT[r * 32 + co] = w2[idx];
    }
    __syncthreads();
    int co = tid & 31, pg = tid >> 5;
    float bias = b2[co];
    float s = 0.f, q = 0.f;
    int stride = store_min ? 64 : 32;
    for (int kk = 0; kk < 4; ++kk) {
        int task = pg + 8 * kk;               // 0..31
        int pr = task >> 2, cb = task & 3;
        int y0 = 2 * pr, x0 = 6 * cb;
        float a[2][6];
#pragma unroll
        for (int r2 = 0; r2 < 2; ++r2)
#pragma unroll
            for (int xi = 0; xi < 6; ++xi) a[r2][xi] = bias;
        for (int ci = 0; ci < 16; ++ci) {
            const float* base = &P2[ci * 486];
            const float* wb = &swT[(ci * 9) * 32 + co];
#pragma unroll
            for (int iy = 0; iy < 4; ++iy) {
                const float* row = &base[(y0 + iy) * 27 + x0];
                float r0 = row[0], r1 = row[1], r2v = row[2], r3 = row[3];
                float r4 = row[4], r5 = row[5], r6 = row[6], r7 = row[7];
                if (iy < 3) {
                    float w0 = wb[(iy * 3 + 0) * 32], w1 = wb[(iy * 3 + 1) * 32], w2v = wb[(iy * 3 + 2) * 32];
                    a[0][0] += r0 * w0 + r1 * w1 + r2v * w2v;
                    a[0][1] += r1 * w0 + r2v * w1 + r3 * w2v;
                    a[0][2] += r2v * w0 + r3 * w1 + r4 * w2v;
                    a[0][3] += r3 * w0 + r4 * w1 + r5 * w2v;
                    a[0][4] += r4 * w0 + r5 * w1 + r6 * w2v;
                    a[0][5] += r5 * w0 + r6 * w1 + r7 * w2v;
                }
                if (iy >= 1) {
                    int ky = iy - 1;
                    float w0 = wb[(ky * 3 + 0) * 32], w1 = wb[(ky * 3 + 1) * 32], w2v = wb[(ky * 3 + 2) * 32];
                    a[1][0] += r0 * w0 + r1 * w1 + r2v * w2v;
                    a[1][1] += r1 * w0 + r2v * w1 + r3 * w2v;
                    a[1][2] += r2v * w0 + r3 * w1 + r4 * w2v;
                    a[1][3] += r3 * w0 + r4 * w1 + r5 * w2v;
                    a[1][4] += r4 * w0 + r5 * w1 + r6 * w2v;
                    a[1][5] += r5 * w0 + r6 * w1 + r7 * w2v;
                }
            }
        }
#pragma unroll
        for (int r2 = 0; r2 < 2; ++r2)
#pragma unroll
            for (int xi = 0; xi < 6; ++xi) { float v = a[r2][xi]; s += v; q += v * v; }
#pragma unroll
        for (int pc = 0; pc < 3; ++pc) {
            float v00 = a[0][2 * pc], v01 = a[0][2 * pc + 1];
            float v10 = a[1][2 * pc], v11 = a[1][2 * pc + 1];
            float mx = fmaxf(fmaxf(v00, v01), fmaxf(v10, v11));
            int cellIdx = pr * 12 + 3 * cb + pc;
            mm[((size_t)n * 96 + cellIdx) * stride + co] = mx;
            if (store_min) {
                float mn = fminf(fminf(v00, v01), fminf(v10, v11));
                mm[((size_t)n * 96 + cellIdx) * 64 + 32 + co] = mn;
            }
        }
    }
    // column 24 contributes to BN stats only (dropped by VALID 2x2 pool)
    {
        int y0 = 2 * pg;
        float a0 = bias, a1 = bias;
        for (int ci = 0; ci < 16; ++ci) {
            const float* base = &P2[ci * 486];
            const float* wb = &swT[(ci * 9) * 32 + co];
#pragma unroll
            for (int iy = 0; iy < 4; ++iy) {
                const float* row = &base[(y0 + iy) * 27 + 24];
                float r0 = row[0], r1 = row[1], r2v = row[2];
                if (iy < 3) {
                    float w0 = wb[(iy * 3 + 0) * 32], w1 = wb[(iy * 3 + 1) * 32], w2v = wb[(iy * 3 + 2) * 32];
                    a0 += r0 * w0 + r1 * w1 + r2v * w2v;
                }
                if (iy >= 1) {
                    int ky = iy - 1;
                    float w0 = wb[(ky * 3 + 0) * 32], w1 = wb[(ky * 3 + 1) * 32], w2v = wb[(ky * 3 + 2) * 32];
                    a1 += r0 * w0 + r1 * w1 + r2v * w2v;
                }
            }
        }
        s += a0 + a1; q += a0 * a0 + a1 * a1;
    }
    ls[tid] = s; lq[tid] = q;
    __syncthreads();
    if (tid < 32) {
        float ss = 0.f, qq = 0.f;
        for (int g2 = 0; g2 < 8; ++g2) { ss += ls[tid + 32 * g2]; qq += lq[tid + 32 * g2]; }
        psum[n * 32 + tid] = (double)ss;
        psq[n * 32 + tid] = (double)qq;
    }
}

// ---------------- K5: affine + relu + pooled mean -> pm ----------------
__global__ __launch_bounds__(256) void pool_mean_kernel(const float* __restrict__ mm,
                                                        const float* __restrict__ scale,
                                                        const float* __restrict__ shift,
                                                        float* __restrict__ pm,
                                                        int store_min) {
    int n = blockIdx.x, tid = threadIdx.x;
    int co = tid & 31, grp = tid >> 5;
    float sc = scale[co], sh = shift[co];
    int stride = store_min ? 64 : 32;
    float acc = 0.f;
    for (int j = 0; j < 12; ++j) {
        int cell = grp * 12 + j;
        float v;
        if (store_min && sc < 0.f) {
            float mn = mm[((size_t)n * 96 + cell) * 64 + 32 + co];
            v = mn * sc + sh;
        } else {
            float mx = mm[((size_t)n * 96 + cell) * stride + co];
            v = mx * sc + sh;
        }
        acc += fmaxf(v, 0.f);
    }
    __shared__ float red[256];
    red[tid] = acc;
    __syncthreads();
    if (tid < 32) {
        float t = 0.f;
        for (int g = 0; g < 8; ++g) t += red[co + 32 * g];
        pm[n * 32 + co] = t * (1.f / 96.f);
    }
}

// ---------------- K6: FC 32->128 ----------------
__global__ __launch_bounds__(128) void fc_kernel(const float* __restrict__ pm,
                                                 const float* __restrict__ fc_w,
                                                 const float* __restrict__ fc_b,
                                                 float* __restrict__ emb) {
    int n = blockIdx.x, e = threadIdx.x;
    __shared__ float sp[32];
    if (e < 32) sp[e] = pm[n * 32 + e];
    __syncthreads();
    const float* w = fc_w + e * 32;
    float acc = fc_b[e];
    for (int c = 0; c < 32; ++c) acc += sp[c] * w[c];
    emb[n * 128 + e] = acc;
}

// ---------------- K7: Q/K projections 128->128 ----------------
__global__ __launch_bounds__(128) void qk_kernel(const float* __restrict__ emb,
                                                 const float* __restrict__ q_w,
                                                 const float* __restrict__ q_b,
                                                 const float* __restrict__ k_w,
                                                 const float* __restrict__ k_b,
                                                 float* __restrict__ Q,
                                                 float* __restrict__ Kp) {
    int n = blockIdx.x, e = threadIdx.x;
    const float* w = (blockIdx.y == 0) ? q_w : k_w;
    const float* b = (blockIdx.y == 0) ? q_b : k_b;
    float* out = (blockIdx.y == 0) ? Q : Kp;
    __shared__ float se[128];
    se[e] = emb[n * 128 + e];
    __syncthreads();
    const float* wr = w + e * 128;
    float acc = b[e];
    for (int k = 0; k < 128; ++k) acc += se[k] * wr[k];
    out[n * 128 + e] = acc;
}

// ---------------- K8: attention scores + leaky relu ----------------
__global__ __launch_bounds__(256) void attn_kernel(const float* __restrict__ Q,
                                                   const float* __restrict__ Kp,
                                                   float* __restrict__ attn) {
    int r = blockIdx.x, t = blockIdx.y, tid = threadIdx.x;
    __shared__ float sq[128];
    if (tid < 128) sq[tid] = Q[(t * 200 + r) * 128 + tid];
    __syncthreads();
    if (tid < 200) {
        const float4* kp4 = (const float4*)(Kp + (size_t)(t * 200 + tid) * 128);
        float acc = 0.f;
#pragma unroll 8
        for (int e4 = 0; e4 < 32; ++e4) {
            float4 k4 = kp4[e4];
            acc += sq[e4 * 4 + 0] * k4.x + sq[e4 * 4 + 1] * k4.y +
                   sq[e4 * 4 + 2] * k4.z + sq[e4 * 4 + 3] * k4.w;
        }
        acc = acc / 11.313708498984761f;
        acc = (acc >= 0.f) ? acc : 0.2f * acc;
        attn[(size_t)(t * 200 + r) * 200 + tid] = acc;
    }
}

// ---------------- K9: top-k(20) mask + softmax -> adj ----------------
__global__ __launch_bounds__(64) void topk_softmax_kernel(const float* __restrict__ attn,
                                                          float* __restrict__ adj) {
    int row = blockIdx.x;     // t*200 + r
    int lane = threadIdx.x;   // 64 threads
    const float* a = attn + (size_t)row * 200;
    float v[4], w[4];
#pragma unroll
    for (int j = 0; j < 4; ++j) {
        int i = lane + 64 * j;
        float x = (i < 200) ? a[i] : -FLT_MAX;
        v[j] = x; w[j] = x;
    }
    unsigned sel = 0;
    for (int it = 0; it < K_; ++it) {
        float best = -FLT_MAX; int bidx = 0x7fffffff;
#pragma unroll
        for (int j = 0; j < 4; ++j) {
            int i = lane + 64 * j;
            if (w[j] > best || (w[j] == best && i < bidx)) { best = w[j]; bidx = i; }
        }
#pragma unroll
        for (int off = 32; off > 0; off >>= 1) {
            float ob = __shfl_down(best, off, 64);
            int oi = __shfl_down(bidx, off, 64);
            if (ob > best || (ob == best && oi < bidx)) { best = ob; bidx = oi; }
        }
        bidx = __shfl(bidx, 0, 64);
        if ((bidx & 63) == lane) { int j = bidx >> 6; w[j] = -FLT_MAX; sel |= (1u << j); }
    }
    float mv[4]; float m = -FLT_MAX;
#pragma unroll
    for (int j = 0; j < 4; ++j) {
        int i = lane + 64 * j;
        float x = -1e9f;
        if (i < 200 && ((sel >> j) & 1u)) x = (v[j] == 0.f) ? -1e9f : v[j];
        mv[j] = x; m = fmaxf(m, x);
    }
#pragma unroll
    for (int off = 32; off > 0; off >>= 1) m = fmaxf(m, __shfl_xor(m, off, 64));
    float s = 0.f; float e[4];
#pragma unroll
    for (int j = 0; j < 4; ++j) {
        int i = lane + 64 * j;
        e[j] = (i < 200) ? expf(mv[j] - m) : 0.f;
        s += e[j];
    }
#pragma unroll
    for (int off = 32; off > 0; off >>= 1) s += __shfl_xor(s, off, 64);
    float inv = 1.f / s;
#pragma unroll
    for (int j = 0; j < 4; ++j) {
        int i = lane + 64 * j;
        if (i < 200) adj[(size_t)row * 200 + i] = e[j] * inv;
    }
}

// ---------------- K10: build normalized adjacency An ----------------
__global__ __launch_bounds__(256) void build_An_kernel(const float* __restrict__ adj,
                                                       float* __restrict__ An) {
    int t = blockIdx.x, tid = threadIdx.x;
    __shared__ float dinv[200];
    if (tid < 200) {
        float acc = 0.f;
        for (int s = 0; s < 200; ++s) {
            float v = adj[(size_t)(t * 200 + s) * 200 + tid];
            if (s == tid) v = (v == 0.f) ? 1.f : v;
            acc += v;
        }
        float d = (acc > 0.f) ? acc : 1.f;
        dinv[tid] = 1.f / sqrtf(d);
    }
    __syncthreads();
    for (int idx = tid; idx < 200 * 200; idx += 256) {
        int r = idx / 200, s = idx % 200;
        float v = adj[(size_t)(t * 200 + s) * 200 + r];
        if (s == r) v = (v == 0.f) ? 1.f : v;
        An[(size_t)(t * 200 + r) * 200 + s] = dinv[r] * v * dinv[s];
    }
}

// ---------------- K11: row @ weight (IN -> 256), no bias ----------------
__global__ __launch_bounds__(256) void linear_kernel(const float* __restrict__ in,
                                                     const float* __restrict__ w,
                                                     float* __restrict__ out, int IN) {
    int n = blockIdx.x, h = threadIdx.x;
    __shared__ float s[256];
    for (int i = h; i < IN; i += 256) s[i] = in[n * IN + i];
    __syncthreads();
    float acc = 0.f;
    for (int k = 0; k < IN; ++k) acc += s[k] * w[k * 256 + h];
    out[(size_t)n * 256 + h] = acc;
}

// ---------------- K12: GCN aggregation: relu(An @ X + b) ----------------
__global__ __launch_bounds__(256) void gcn_agg_kernel(const float* __restrict__ An,
                                                      const float* __restrict__ X,
                                                      const float* __restrict__ b,
                                                      float* __restrict__ out) {
    int r = blockIdx.x, t = blockIdx.y, h = threadIdx.x;
    __shared__ float sa[200];
    for (int i = h; i < 200; i += 256) sa[i] = An[(size_t)(t * 200 + r) * 200 + i];
    __syncthreads();
    const float* Xt = X + (size_t)t * 200 * 256;
    float acc = 0.f;
    for (int s = 0; s < 200; ++s) acc += sa[s] * Xt[s * 256 + h];
    out[(size_t)(t * 200 + r) * 256 + h] = fmaxf(acc + b[h], 0.f);
}

// ---------------- K13: mean over R ----------------
__global__ __launch_bounds__(256) void gemb_kernel(const float* __restrict__ g2,
                                                   float* __restrict__ g_emb) {
    int t = blockIdx.x, h = threadIdx.x;
    float acc = 0.f;
    for (int r = 0; r < 200; ++r) acc += g2[(size_t)(t * 200 + r) * 256 + h];
    g_emb[t * 256 + h] = acc * (1.f / 200.f);
}

// ---------------- K14: transpose 768x256 -> [k][j] ----------------
__global__ __launch_bounds__(256) void transpose_768x256_kernel(const float* __restrict__ in,
                                                                float* __restrict__ outT) {
    int gid = blockIdx.x * 256 + threadIdx.x;   // 196608 total
    int k = gid / 768, j = gid % 768;
    outT[gid] = in[j * 256 + k];
}

// ---------------- K15: GRU input-side matvecs GI[t][0..767] (coalesced) ----------------
__global__ __launch_bounds__(768) void gi_kernel(const float* __restrict__ g_emb,
                                                 const float* __restrict__ wihT,
                                                 const float* __restrict__ bih,
                                                 float* __restrict__ GI) {
    int t = blockIdx.x, j = threadIdx.x;
    __shared__ float sg[256];
    if (j < 256) sg[j] = g_emb[t * 256 + j];
    __syncthreads();
    float acc = bih[j];
    for (int k = 0; k < 256; ++k) acc += sg[k] * wihT[k * 768 + j];
    GI[t * 768 + j] = acc;
}

// ---------------- K16: sequential GRU + classifier (single block, coalesced) ----------------
__global__ __launch_bounds__(768) void gru_cls_kernel(const float* __restrict__ GI,
                                                      const float* __restrict__ whhT,
                                                      const float* __restrict__ bhh,
                                                      const float* __restrict__ cls_w,
                                                      const float* __restrict__ cls_b,
                                                      float* __restrict__ out) {
    int j = threadIdx.x;
    __shared__ float h[256];
    __shared__ float gh[768];
    __shared__ float s0[4], s1[4];
    if (j < 256) h[j] = 0.f;
    float bh = bhh[j];
    __syncthreads();
    for (int t = 0; t < 16; ++t) {
        float acc = bh;
        for (int k = 0; k < 256; ++k) acc += h[k] * whhT[k * 768 + j];
        gh[j] = acc;
        __syncthreads();
        if (j < 256) {
            float r = 1.f / (1.f + expf(-(GI[t * 768 + j] + gh[j])));
            float z = 1.f / (1.f + expf(-(GI[t * 768 + 256 + j] + gh[256 + j])));
            float nn = tanhf(GI[t * 768 + 512 + j] + r * gh[512 + j]);
            h[j] = (1.f - z) * nn + z * h[j];
        }
        __syncthreads();
    }
    float v0 = 0.f, v1 = 0.f;
    if (j < 256) { v0 = h[j] * cls_w[j]; v1 = h[j] * cls_w[256 + j]; }
    waveReduce2(v0, v1);
    int lane = j & 63, wid = j >> 6;
    if (lane == 0 && wid < 4) { s0[wid] = v0; s1[wid] = v1; }
    __syncthreads();
    if (j == 0) {
        out[0] = s0[0] + s0[1] + s0[2] + s0[3] + cls_b[0];
        out[1] = s1[0] + s1[1] + s1[2] + s1[3] + cls_b[1];
    }
}

// ---------------- K17: avg_adj + edge variance ----------------
__global__ __launch_bounds__(256) void edge_kernel(const float* __restrict__ adj,
                                                   float* __restrict__ out) {
    int gid = blockIdx.x * 256 + threadIdx.x;
    float var = 0.f;
    if (gid < 40000) {
        float v[16]; float s = 0.f;
#pragma unroll
        for (int t = 0; t < 16; ++t) { v[t] = adj[t * 40000 + gid]; s += v[t]; }
        float mean = s * (1.f / 16.f);
        float q = 0.f;
#pragma unroll
        for (int t = 0; t < 16; ++t) { float d = v[t] - mean; q += d * d; }
        var = q * (1.f / 15.f);
        out[2 + gid] = mean;
    }
    float dummy = 0.f;
    waveReduce2(var, dummy);
    __shared__ float sa[4];
    int lane = threadIdx.x & 63, wid = threadIdx.x >> 6;
    if (lane == 0) sa[wid] = var;
    __syncthreads();
    if (threadIdx.x == 0) {
        float bs = sa[0] + sa[1] + sa[2] + sa[3];
        atomicAdd(&out[40002], bs * (1.f / 40000.f));
    }
}

// ---------------- host ----------------
extern "C" void kernel_launch(void* const* d_in, const int* in_sizes, int n_in,
                              void* d_out, int out_size, void* d_ws, size_t ws_size,
                              hipStream_t stream) {
    const float* tw      = (const float*)d_in[0];
    const float* wav_r   = (const float*)d_in[1];
    const float* wav_i   = (const float*)d_in[2];
    const float* conv1_w = (const float*)d_in[3];
    const float* conv1_b = (const float*)d_in[4];
    const float* bn1_g   = (const float*)d_in[5];
    const float* bn1_b   = (const float*)d_in[6];
    const float* conv2_w = (const float*)d_in[7];
    const float* conv2_b = (const float*)d_in[8];
    const float* bn2_g   = (const float*)d_in[9];
    const float* bn2_b   = (const float*)d_in[10];
    const float* fc_w    = (const float*)d_in[11];
    const float* fc_b    = (const float*)d_in[12];
    const float* q_w     = (const float*)d_in[13];
    const float* q_b     = (const float*)d_in[14];
    const float* k_w     = (const float*)d_in[15];
    const float* k_b     = (const float*)d_in[16];
    const float* gcn1_w  = (const float*)d_in[17];
    const float* gcn1_b  = (const float*)d_in[18];
    const float* gcn2_w  = (const float*)d_in[19];
    const float* gcn2_b  = (const float*)d_in[20];
    const float* gru_wih = (const float*)d_in[21];
    const float* gru_whh = (const float*)d_in[22];
    const float* gru_bih = (const float*)d_in[23];
    const float* gru_bhh = (const float*)d_in[24];
    const float* cls_w   = (const float*)d_in[25];
    const float* cls_b   = (const float*)d_in[26];
    float* out = (float*)d_out;
    (void)in_sizes; (void)n_in; (void)out_size;

    // ---- workspace layout (with max-only fallback if ws is tight) ----
    const size_t POOLED1_B = (size_t)N_ * 16 * 16 * 25 * 4;     // 81.92 MB
    const size_t SCALU_B   = (size_t)N_ * 1600 * 4;             // 20.48 MB (scal, later pm/emb/Q/Kp)
    const size_t MM_FULL_B = (size_t)N_ * 96 * 64 * 4;          // 78.64 MB (max+min)
    const size_t MM_MAX_B  = (size_t)N_ * 96 * 32 * 4;          // 39.32 MB (max only)
    const size_t P1S_B     = (size_t)N_ * 16 * 8;
    const size_t P2S_B     = (size_t)N_ * 32 * 8;
    const size_t WT_B      = (size_t)768 * 256 * 4;
    size_t fixed = POOLED1_B + SCALU_B + 2 * P1S_B + 2 * P2S_B + 2 * WT_B + 8 * 256 + 4096;
    int store_min = (ws_size >= fixed + MM_FULL_B) ? 1 : 0;
    const size_t MM_B = store_min ? MM_FULL_B : MM_MAX_B;

    size_t off = 0;
    char* Wb = (char*)d_ws;
    auto take = [&](size_t bytes) -> char* {
        char* p = Wb + off;
        off += (bytes + 255) & ~(size_t)255;
        return p;
    };
    float* pooled1 = (float*)take(POOLED1_B);
    char*  scalU   = take(SCALU_B);
    char*  mmU     = take(MM_B);
    double* p1sum = (double*)take(P1S_B);
    double* p1sq  = (double*)take(P1S_B);
    double* p2sum = (double*)take(P2S_B);
    double* p2sq  = (double*)take(P2S_B);
    float* scale1 = (float*)take(64 * 4);
    float* shift1 = (float*)take(64 * 4);
    float* scale2 = (float*)take(64 * 4);
    float* shift2 = (float*)take(64 * 4);
    float* wihT   = (float*)take(WT_B);
    float* whhT   = (float*)take(WT_B);

    // scalU region: scal lives until conv1_norm_pool; then pm/emb/Q/Kp
    float* scal = (float*)scalU;
    float* pm   = (float*)(scalU + 0);
    float* emb  = (float*)(scalU + 409600);
    float* Q    = (float*)(scalU + 409600 + 1638400);
    float* Kp   = (float*)(scalU + 409600 + 2 * 1638400);
    // wait: pm overlaps scal? pm is written in pool_mean (after scal is dead). OK.

    // mmU region: mm lives until pool_mean; then attn/adj/An/X1/g1/X2/g2/g_emb/GI
    float* mm   = (float*)mmU;
    size_t moff = 0;
    auto mtake = [&](size_t bytes) -> float* {
        float* p = (float*)(mmU + moff);
        moff += (bytes + 255) & ~(size_t)255;
        return p;
    };
    float* attn  = mtake((size_t)T_ * 200 * 200 * 4);
    float* adj   = mtake((size_t)T_ * 200 * 200 * 4);
    float* An    = mtake((size_t)T_ * 200 * 200 * 4);
    float* X1    = mtake((size_t)N_ * 256 * 4);
    float* g1    = mtake((size_t)N_ * 256 * 4);
    float* X2    = mtake((size_t)N_ * 256 * 4);
    float* g2    = mtake((size_t)N_ * 256 * 4);
    float* g_emb = mtake((size_t)T_ * 256 * 4);
    float* GI    = mtake((size_t)T_ * 768 * 4);

    // 0) weight transposes (independent of everything else)
    transpose_768x256_kernel<<<768, 256, 0, stream>>>(gru_wih, wihT);
    transpose_768x256_kernel<<<768, 256, 0, stream>>>(gru_whh, whhT);
    // 1) CWT + conv1 stats (fused)
    cwt_conv1_stats_kernel<<<N_, 256, 0, stream>>>(tw, wav_r, wav_i, conv1_w, conv1_b,
                                                   scal, p1sum, p1sq);
    bn_finalize_kernel<<<16, 256, 0, stream>>>(p1sum, p1sq, bn1_g, bn1_b, scale1, shift1,
                                               16, 1.0 / 5120000.0);
    conv1_norm_pool_kernel<<<N_, 256, 0, stream>>>(scal, conv1_w, conv1_b, scale1, shift1,
                                                   pooled1);
    // 2) conv2 single pass + BN + pooled mean
    conv2_compute_kernel<<<N_, 256, 0, stream>>>(pooled1, conv2_w, conv2_b, mm,
                                                 p2sum, p2sq, store_min);
    bn_finalize_kernel<<<32, 256, 0, stream>>>(p2sum, p2sq, bn2_g, bn2_b, scale2, shift2,
                                               32, 1.0 / 1280000.0);
    pool_mean_kernel<<<N_, 256, 0, stream>>>(mm, scale2, shift2, pm, store_min);
    // 3) FC + Q/K
    fc_kernel<<<N_, 128, 0, stream>>>(pm, fc_w, fc_b, emb);
    qk_kernel<<<dim3(N_, 2), 128, 0, stream>>>(emb, q_w, q_b, k_w, k_b, Q, Kp);
    // 4) attention -> topk softmax -> An
    attn_kernel<<<dim3(200, 16), 256, 0, stream>>>(Q, Kp, attn);
    topk_softmax_kernel<<<N_, 64, 0, stream>>>(attn, adj);
    build_An_kernel<<<16, 256, 0, stream>>>(adj, An);
    // 5) GCN x2
    linear_kernel<<<N_, 256, 0, stream>>>(emb, gcn1_w, X1, 128);
    gcn_agg_kernel<<<dim3(200, 16), 256, 0, stream>>>(An, X1, gcn1_b, g1);
    linear_kernel<<<N_, 256, 0, stream>>>(g1, gcn2_w, X2, 256);
    gcn_agg_kernel<<<dim3(200, 16), 256, 0, stream>>>(An, X2, gcn2_b, g2);
    // 6) graph embedding + GRU + classifier
    gemb_kernel<<<16, 256, 0, stream>>>(g2, g_emb);
    gi_kernel<<<16, 768, 0, stream>>>(g_emb, wihT, gru_bih, GI);
    gru_cls_kernel<<<1, 768, 0, stream>>>(GI, whhT, gru_bhh, cls_w, cls_b, out);
    // 7) avg_adj + edge_var
    hipMemsetAsync(out + 40002, 0, sizeof(float), stream);
    edge_kernel<<<(40000 + 255) / 256, 256, 0, stream>>>(adj, out);
}

// Round 3
// 865.821 us; speedup vs baseline: 2.1186x; 1.0430x over previous
//
#include <hip/hip_runtime.h>
#include <cfloat>
#include <cmath>

// Shapes
#define T_ 16
#define R_ 200
#define W_ 50
#define FCWT 32
#define E_ 128
#define K_ 20
#define N_ 3200            // T_*R_
#define GRU_BLOCKS 6

// ---------------- helpers ----------------
__device__ __forceinline__ void waveReduce2(float& a, float& b) {
#pragma unroll
    for (int o = 32; o > 0; o >>= 1) {
        a += __shfl_down(a, o, 64);
        b += __shfl_down(b, o, 64);
    }
}

// ---------------- K1: CWT (rolling window) + conv1 BN stats (row-rolling) ----------------
__global__ __launch_bounds__(256) void cwt_conv1_stats_kernel(const float* __restrict__ x,
                                                              const float* __restrict__ wr,
                                                              const float* __restrict__ wi,
                                                              const float* __restrict__ w1,
                                                              const float* __restrict__ b1,
                                                              float* __restrict__ scal,
                                                              double* __restrict__ psum,
                                                              double* __restrict__ psq) {
    int n = blockIdx.x, tid = threadIdx.x;
    __shared__ float sxp[112];               // zero-padded x: [24,74) = x
    __shared__ float swr[FCWT * W_];
    __shared__ float swi[FCWT * W_];
    __shared__ float P1[34 * 52];            // padded scalogram
    __shared__ float ls[256], lq[256];
    if (tid < 112) sxp[tid] = (tid >= 24 && tid < 74) ? x[n * 50 + (tid - 24)] : 0.f;
    for (int idx = tid; idx < FCWT * W_; idx += 256) { swr[idx] = wr[idx]; swi[idx] = wi[idx]; }
    for (int idx = tid; idx < 34 * 52; idx += 256) P1[idx] = 0.f;
    __syncthreads();
    // ---- CWT phase: 64 threads, 25 outputs each, rolling x window ----
    if (tid < 64) {
        int f = tid >> 1, i0 = (tid & 1) * 25;
        float xw[25], ar[25], ai[25];
#pragma unroll
        for (int d = 0; d < 25; ++d) { xw[d] = sxp[i0 + d]; ar[d] = 0.f; ai[d] = 0.f; }
        const float* wrf = &swr[f * 50];
        const float* wif = &swi[f * 50];
        for (int j = 0; j < 50; ++j) {
            float wrv = wrf[j], wiv = wif[j];
#pragma unroll
            for (int d = 0; d < 25; ++d) { ar[d] += xw[d] * wrv; ai[d] += xw[d] * wiv; }
            float xnew = sxp[i0 + j + 25];
#pragma unroll
            for (int d = 0; d < 24; ++d) xw[d] = xw[d + 1];
            xw[24] = xnew;
        }
#pragma unroll
        for (int d = 0; d < 25; ++d) {
            float v = sqrtf(ar[d] * ar[d] + ai[d] * ai[d]);
            P1[(f + 1) * 52 + (i0 + d + 1)] = v;
        }
    }
    __syncthreads();
    // coalesced scal store from P1
    for (int idx = tid; idx < 1600; idx += 256) {
        int ff = idx / 50, ii = idx % 50;
        scal[n * 1600 + idx] = P1[(ff + 1) * 52 + ii + 1];
    }
    // ---- conv1 stats: c = tid&15, pg = tid>>4 owns out rows 2pg, 2pg+1 ----
    int c = tid & 15, pg = tid >> 4;
    float wv[9];
#pragma unroll
    for (int k = 0; k < 9; ++k) wv[k] = w1[c * 9 + k];
    float bias = b1[c];
    const float* r0p = &P1[(2 * pg + 0) * 52];
    const float* r1p = &P1[(2 * pg + 1) * 52];
    const float* r2p = &P1[(2 * pg + 2) * 52];
    const float* r3p = &P1[(2 * pg + 3) * 52];
    float c0[4], c1[4];
    c0[0] = r0p[0]; c0[1] = r1p[0]; c0[2] = r2p[0]; c0[3] = r3p[0];
    c1[0] = r0p[1]; c1[1] = r1p[1]; c1[2] = r2p[1]; c1[3] = r3p[1];
    float s = 0.f, q = 0.f;
    for (int xx = 0; xx < 50; ++xx) {
        float c2[4];
        c2[0] = r0p[xx + 2]; c2[1] = r1p[xx + 2]; c2[2] = r2p[xx + 2]; c2[3] = r3p[xx + 2];
        float v0 = bias + c0[0] * wv[0] + c1[0] * wv[1] + c2[0] * wv[2]
                        + c0[1] * wv[3] + c1[1] * wv[4] + c2[1] * wv[5]
                        + c0[2] * wv[6] + c1[2] * wv[7] + c2[2] * wv[8];
        float v1 = bias + c0[1] * wv[0] + c1[1] * wv[1] + c2[1] * wv[2]
                        + c0[2] * wv[3] + c1[2] * wv[4] + c2[2] * wv[5]
                        + c0[3] * wv[6] + c1[3] * wv[7] + c2[3] * wv[8];
        s += v0 + v1; q += v0 * v0 + v1 * v1;
#pragma unroll
        for (int rr = 0; rr < 4; ++rr) { c0[rr] = c1[rr]; c1[rr] = c2[rr]; }
    }
    ls[tid] = s; lq[tid] = q;
    __syncthreads();
    if (tid < 16) {
        float ss = 0.f, qq = 0.f;
        for (int g = 0; g < 16; ++g) { ss += ls[tid + 16 * g]; qq += lq[tid + 16 * g]; }
        psum[n * 16 + tid] = (double)ss;
        psq[n * 16 + tid] = (double)qq;
    }
}

// ---------------- K2: BN finalize ----------------
__global__ __launch_bounds__(256) void bn_finalize_kernel(const double* __restrict__ psum,
                                                          const double* __restrict__ psq,
                                                          const float* __restrict__ g,
                                                          const float* __restrict__ beta,
                                                          float* __restrict__ scale,
                                                          float* __restrict__ shift,
                                                          int C, double inv_count) {
    int c = blockIdx.x, tid = threadIdx.x;
    double s = 0.0, q = 0.0;
    for (int n = tid; n < N_; n += 256) { s += psum[n * C + c]; q += psq[n * C + c]; }
#pragma unroll
    for (int o = 32; o > 0; o >>= 1) { s += __shfl_down(s, o, 64); q += __shfl_down(q, o, 64); }
    __shared__ double sa[4], sb[4];
    int lane = tid & 63, wid = tid >> 6;
    if (lane == 0) { sa[wid] = s; sb[wid] = q; }
    __syncthreads();
    if (tid == 0) {
        s = sa[0] + sa[1] + sa[2] + sa[3];
        q = sb[0] + sb[1] + sb[2] + sb[3];
        double mu = s * inv_count;
        double var = q * inv_count - mu * mu;
        double rstd = 1.0 / sqrt(var + 1e-5);
        double gg = (double)g[c];
        scale[c] = (float)(gg * rstd);
        shift[c] = (float)((double)beta[c] - mu * rstd * gg);
    }
}

// ---------------- K3: conv1 recompute + norm + relu + pool (row-rolling) ----------------
__global__ __launch_bounds__(256) void conv1_norm_pool_kernel(const float* __restrict__ scal,
                                                              const float* __restrict__ w1,
                                                              const float* __restrict__ b1,
                                                              const float* __restrict__ scale,
                                                              const float* __restrict__ shift,
                                                              float* __restrict__ pooled1) {
    int n = blockIdx.x, tid = threadIdx.x;
    __shared__ float P1[34 * 52];
    __shared__ float outb[6400];
    for (int idx = tid; idx < 34 * 52; idx += 256) {
        int yy = idx / 52, xx = idx % 52;
        float v = 0.f;
        if (yy >= 1 && yy <= 32 && xx >= 1 && xx <= 50)
            v = scal[n * 1600 + (yy - 1) * 50 + (xx - 1)];
        P1[idx] = v;
    }
    __syncthreads();
    int c = tid & 15, py = tid >> 4;          // pool row py: out rows 2py, 2py+1
    float wv[9];
#pragma unroll
    for (int k = 0; k < 9; ++k) wv[k] = w1[c * 9 + k];
    float bias = b1[c], sc = scale[c], sh = shift[c];
    const float* r0p = &P1[(2 * py + 0) * 52];
    const float* r1p = &P1[(2 * py + 1) * 52];
    const float* r2p = &P1[(2 * py + 2) * 52];
    const float* r3p = &P1[(2 * py + 3) * 52];
    float c0[4], c1[4];
    c0[0] = r0p[0]; c0[1] = r1p[0]; c0[2] = r2p[0]; c0[3] = r3p[0];
    c1[0] = r0p[1]; c1[1] = r1p[1]; c1[2] = r2p[1]; c1[3] = r3p[1];
    float pmax = -FLT_MAX;
    for (int xx = 0; xx < 50; ++xx) {
        float c2[4];
        c2[0] = r0p[xx + 2]; c2[1] = r1p[xx + 2]; c2[2] = r2p[xx + 2]; c2[3] = r3p[xx + 2];
        float v0 = bias + c0[0] * wv[0] + c1[0] * wv[1] + c2[0] * wv[2]
                        + c0[1] * wv[3] + c1[1] * wv[4] + c2[1] * wv[5]
                        + c0[2] * wv[6] + c1[2] * wv[7] + c2[2] * wv[8];
        float v1 = bias + c0[1] * wv[0] + c1[1] * wv[1] + c2[1] * wv[2]
                        + c0[2] * wv[3] + c1[2] * wv[4] + c2[2] * wv[5]
                        + c0[3] * wv[6] + c1[3] * wv[7] + c2[3] * wv[8];
        float m2 = fmaxf(v0 * sc + sh, v1 * sc + sh);
        if ((xx & 1) == 0) pmax = m2;
        else outb[(c * 16 + py) * 25 + (xx >> 1)] = fmaxf(fmaxf(pmax, m2), 0.f);
#pragma unroll
        for (int rr = 0; rr < 4; ++rr) { c0[rr] = c1[rr]; c1[rr] = c2[rr]; }
    }
    __syncthreads();
    for (int idx = tid; idx < 6400; idx += 256)
        pooled1[(size_t)n * 6400 + idx] = outb[idx];
}

// ---------------- K4: conv2 single pass: reg-blocked rows, stats + pooled max/min ----------------
__global__ __launch_bounds__(256) void conv2_compute_kernel(const float* __restrict__ pooled1,
                                                            const float* __restrict__ w2,
                                                            const float* __restrict__ b2,
                                                            float* __restrict__ mm,
                                                            double* __restrict__ psum,
                                                            double* __restrict__ psq,
                                                            int store_min) {
    int n = blockIdx.x, tid = threadIdx.x;
    __shared__ float P2[16 * 18 * 28];        // [ci][18][28], image at y 1..16, x 1..25
    __shared__ float swT[144 * 32];           // [(ci*9+k)][co]
    __shared__ float ls[256], lq[256];
    for (int idx = tid; idx < 16 * 18 * 28; idx += 256) {
        int ci = idx / 504, rem = idx % 504, yy = rem / 28, xx = rem % 28;
        float v = 0.f;
        if (yy >= 1 && yy <= 16 && xx >= 1 && xx <= 25)
            v = pooled1[((size_t)n * 16 + ci) * 400 + (yy - 1) * 25 + (xx - 1)];
        P2[idx] = v;
    }
    for (int idx = tid; idx < 4608; idx += 256) {
        int co = idx / 144, r = idx % 144;
        swT[r * 32 + co] = w2[idx];
    }
    __syncthreads();
    int co = tid & 31, pg = tid >> 5;         // pg = pool row pr; out rows 2pg, 2pg+1
    float bias = b2[co];
    float acc0[25], acc1[25];
#pragma unroll
    for (int cv = 0; cv < 25; ++cv) { acc0[cv] = bias; acc1[cv] = bias; }
    for (int ci = 0; ci < 16; ++ci) {
        const float* wb = &swT[ci * 288 + co];
        float w[9];
#pragma unroll
        for (int k = 0; k < 9; ++k) w[k] = wb[k * 32];
        const float* base = &P2[ci * 504 + (2 * pg) * 28];
#pragma unroll
        for (int iy = 0; iy < 4; ++iy) {
            float r[28];
            const float4* rp = (const float4*)(base + iy * 28);
#pragma unroll
            for (int m = 0; m < 7; ++m) {
                float4 v4 = rp[m];
                r[4 * m] = v4.x; r[4 * m + 1] = v4.y; r[4 * m + 2] = v4.z; r[4 * m + 3] = v4.w;
            }
            if (iy < 3) {
                int kb = iy * 3;
#pragma unroll
                for (int cv = 0; cv < 25; ++cv)
                    acc0[cv] += r[cv] * w[kb] + r[cv + 1] * w[kb + 1] + r[cv + 2] * w[kb + 2];
            }
            if (iy >= 1) {
                int kb = (iy - 1) * 3;
#pragma unroll
                for (int cv = 0; cv < 25; ++cv)
                    acc1[cv] += r[cv] * w[kb] + r[cv + 1] * w[kb + 1] + r[cv + 2] * w[kb + 2];
            }
        }
    }
    float s = 0.f, q = 0.f;
#pragma unroll
    for (int cv = 0; cv < 25; ++cv) {
        s += acc0[cv] + acc1[cv];
        q += acc0[cv] * acc0[cv] + acc1[cv] * acc1[cv];
    }
    int stride = store_min ? 64 : 32;
#pragma unroll
    for (int pc = 0; pc < 12; ++pc) {
        float v00 = acc0[2 * pc], v01 = acc0[2 * pc + 1];
        float v10 = acc1[2 * pc], v11 = acc1[2 * pc + 1];
        float mx = fmaxf(fmaxf(v00, v01), fmaxf(v10, v11));
        int cell = pg * 12 + pc;
        mm[((size_t)n * 96 + cell) * stride + co] = mx;
        if (store_min) {
            float mn = fminf(fminf(v00, v01), fminf(v10, v11));
            mm[((size_t)n * 96 + cell) * 64 + 32 + co] = mn;
        }
    }
    ls[tid] = s; lq[tid] = q;
    __syncthreads();
    if (tid < 32) {
        float ss = 0.f, qq = 0.f;
        for (int g2 = 0; g2 < 8; ++g2) { ss += ls[tid + 32 * g2]; qq += lq[tid + 32 * g2]; }
        psum[n * 32 + tid] = (double)ss;
        psq[n * 32 + tid] = (double)qq;
    }
}

// ---------------- K5: affine + relu + pooled mean -> pm ----------------
__global__ __launch_bounds__(256) void pool_mean_kernel(const float* __restrict__ mm,
                                                        const float* __restrict__ scale,
                                                        const float* __restrict__ shift,
                                                        float* __restrict__ pm,
                                                        int store_min) {
    int n = blockIdx.x, tid = threadIdx.x;
    int co = tid & 31, grp = tid >> 5;
    float sc = scale[co], sh = shift[co];
    int stride = store_min ? 64 : 32;
    float acc = 0.f;
    for (int j = 0; j < 12; ++j) {
        int cell = grp * 12 + j;
        float v;
        if (store_min && sc < 0.f) {
            float mn = mm[((size_t)n * 96 + cell) * 64 + 32 + co];
            v = mn * sc + sh;
        } else {
            float mx = mm[((size_t)n * 96 + cell) * stride + co];
            v = mx * sc + sh;
        }
        acc += fmaxf(v, 0.f);
    }
    __shared__ float red[256];
    red[tid] = acc;
    __syncthreads();
    if (tid < 32) {
        float t = 0.f;
        for (int g = 0; g < 8; ++g) t += red[co + 32 * g];
        pm[n * 32 + co] = t * (1.f / 96.f);
    }
}

// ---------------- K6: FC 32->128 ----------------
__global__ __launch_bounds__(128) void fc_kernel(const float* __restrict__ pm,
                                                 const float* __restrict__ fc_w,
                                                 const float* __restrict__ fc_b,
                                                 float* __restrict__ emb) {
    int n = blockIdx.x, e = threadIdx.x;
    __shared__ float sp[32];
    if (e < 32) sp[e] = pm[n * 32 + e];
    __syncthreads();
    const float* w = fc_w + e * 32;
    float acc = fc_b[e];
    for (int c = 0; c < 32; ++c) acc += sp[c] * w[c];
    emb[n * 128 + e] = acc;
}

// ---------------- K7: Q/K projections ----------------
__global__ __launch_bounds__(128) void qk_kernel(const float* __restrict__ emb,
                                                 const float* __restrict__ q_w,
                                                 const float* __restrict__ q_b,
                                                 const float* __restrict__ k_w,
                                                 const float* __restrict__ k_b,
                                                 float* __restrict__ Q,
                                                 float* __restrict__ Kp) {
    int n = blockIdx.x, e = threadIdx.x;
    const float* w = (blockIdx.y == 0) ? q_w : k_w;
    const float* b = (blockIdx.y == 0) ? q_b : k_b;
    float* out = (blockIdx.y == 0) ? Q : Kp;
    __shared__ float se[128];
    se[e] = emb[n * 128 + e];
    __syncthreads();
    const float* wr = w + e * 128;
    float acc = b[e];
    for (int k = 0; k < 128; ++k) acc += se[k] * wr[k];
    out[n * 128 + e] = acc;
}

// ---------------- K8: attention scores + leaky relu ----------------
__global__ __launch_bounds__(256) void attn_kernel(const float* __restrict__ Q,
                                                   const float* __restrict__ Kp,
                                                   float* __restrict__ attn) {
    int r = blockIdx.x, t = blockIdx.y, tid = threadIdx.x;
    __shared__ float sq[128];
    if (tid < 128) sq[tid] = Q[(t * 200 + r) * 128 + tid];
    __syncthreads();
    if (tid < 200) {
        const float4* kp4 = (const float4*)(Kp + (size_t)(t * 200 + tid) * 128);
        float acc = 0.f;
#pragma unroll 8
        for (int e4 = 0; e4 < 32; ++e4) {
            float4 k4 = kp4[e4];
            acc += sq[e4 * 4 + 0] * k4.x + sq[e4 * 4 + 1] * k4.y +
                   sq[e4 * 4 + 2] * k4.z + sq[e4 * 4 + 3] * k4.w;
        }
        acc = acc / 11.313708498984761f;
        acc = (acc >= 0.f) ? acc : 0.2f * acc;
        attn[(size_t)(t * 200 + r) * 200 + tid] = acc;
    }
}

// ---------------- K9: top-k(20) mask + softmax -> adj ----------------
__global__ __launch_bounds__(64) void topk_softmax_kernel(const float* __restrict__ attn,
                                                          float* __restrict__ adj) {
    int row = blockIdx.x;
    int lane = threadIdx.x;
    const float* a = attn + (size_t)row * 200;
    float v[4], w[4];
#pragma unroll
    for (int j = 0; j < 4; ++j) {
        int i = lane + 64 * j;
        float x = (i < 200) ? a[i] : -FLT_MAX;
        v[j] = x; w[j] = x;
    }
    unsigned sel = 0;
    for (int it = 0; it < K_; ++it) {
        float best = -FLT_MAX; int bidx = 0x7fffffff;
#pragma unroll
        for (int j = 0; j < 4; ++j) {
            int i = lane + 64 * j;
            if (w[j] > best || (w[j] == best && i < bidx)) { best = w[j]; bidx = i; }
        }
#pragma unroll
        for (int off = 32; off > 0; off >>= 1) {
            float ob = __shfl_down(best, off, 64);
            int oi = __shfl_down(bidx, off, 64);
            if (ob > best || (ob == best && oi < bidx)) { best = ob; bidx = oi; }
        }
        bidx = __shfl(bidx, 0, 64);
        if ((bidx & 63) == lane) { int j = bidx >> 6; w[j] = -FLT_MAX; sel |= (1u << j); }
    }
    float mv[4]; float m = -FLT_MAX;
#pragma unroll
    for (int j = 0; j < 4; ++j) {
        int i = lane + 64 * j;
        float x = -1e9f;
        if (i < 200 && ((sel >> j) & 1u)) x = (v[j] == 0.f) ? -1e9f : v[j];
        mv[j] = x; m = fmaxf(m, x);
    }
#pragma unroll
    for (int off = 32; off > 0; off >>= 1) m = fmaxf(m, __shfl_xor(m, off, 64));
    float s = 0.f; float e[4];
#pragma unroll
    for (int j = 0; j < 4; ++j) {
        int i = lane + 64 * j;
        e[j] = (i < 200) ? expf(mv[j] - m) : 0.f;
        s += e[j];
    }
#pragma unroll
    for (int off = 32; off > 0; off >>= 1) s += __shfl_xor(s, off, 64);
    float inv = 1.f / s;
#pragma unroll
    for (int j = 0; j < 4; ++j) {
        int i = lane + 64 * j;
        if (i < 200) adj[(size_t)row * 200 + i] = e[j] * inv;
    }
}

// ---------------- K10a: degree / dinv ----------------
__global__ __launch_bounds__(256) void deg_kernel(const float* __restrict__ adj,
                                                  float* __restrict__ dinv) {
    int t = blockIdx.x, tid = threadIdx.x;
    if (tid < 200) {
        float acc = 0.f;
        for (int s = 0; s < 200; ++s) {
            float v = adj[(size_t)(t * 200 + s) * 200 + tid];
            if (s == tid) v = (v == 0.f) ? 1.f : v;
            acc += v;
        }
        float d = (acc > 0.f) ? acc : 1.f;
        dinv[t * 200 + tid] = 1.f / sqrtf(d);
    }
}

// ---------------- K10b: An tiles (LDS transpose) ----------------
__global__ __launch_bounds__(256) void an_tile_kernel(const float* __restrict__ adj,
                                                      const float* __restrict__ dinv,
                                                      float* __restrict__ An) {
    int t = blockIdx.y;
    int tr = blockIdx.x >> 2, tc = blockIdx.x & 3;
    int r0 = tr * 50, s0 = tc * 50;
    int tid = threadIdx.x;
    __shared__ float Tt[50 * 51];
    __shared__ float dr[50], ds[50];
    for (int idx = tid; idx < 2500; idx += 256) {
        int a = idx / 50, b = idx % 50;
        Tt[a * 51 + b] = adj[(size_t)(t * 200 + s0 + a) * 200 + r0 + b];
    }
    if (tid < 50) dr[tid] = dinv[t * 200 + r0 + tid];
    else if (tid >= 64 && tid < 114) ds[tid - 64] = dinv[t * 200 + s0 + (tid - 64)];
    __syncthreads();
    for (int idx = tid; idx < 2500; idx += 256) {
        int rl = idx / 50, sl = idx % 50;
        float v = Tt[sl * 51 + rl];
        if (r0 + rl == s0 + sl) v = (v == 0.f) ? 1.f : v;
        An[(size_t)(t * 200 + r0 + rl) * 200 + s0 + sl] = dr[rl] * v * ds[sl];
    }
}

// ---------------- K11: 8-row batched linear (IN -> 256), no bias ----------------
__global__ __launch_bounds__(256) void linear8_kernel(const float* __restrict__ in,
                                                      const float* __restrict__ w,
                                                      float* __restrict__ out, int IN) {
    int n0 = blockIdx.x * 8, h = threadIdx.x;
    __shared__ float sin_[8 * 256];
    for (int idx = h; idx < 8 * IN; idx += 256) sin_[idx] = in[(size_t)n0 * IN + idx];
    __syncthreads();
    float acc[8];
#pragma unroll
    for (int m = 0; m < 8; ++m) acc[m] = 0.f;
    for (int k = 0; k < IN; ++k) {
        float wv = w[k * 256 + h];
#pragma unroll
        for (int m = 0; m < 8; ++m) acc[m] += sin_[m * IN + k] * wv;
    }
#pragma unroll
    for (int m = 0; m < 8; ++m) out[(size_t)(n0 + m) * 256 + h] = acc[m];
}

// ---------------- K12: GCN aggregation, 8 rows per block ----------------
__global__ __launch_bounds__(256) void gcn_agg_kernel(const float* __restrict__ An,
                                                      const float* __restrict__ X,
                                                      const float* __restrict__ b,
                                                      float* __restrict__ out) {
    int t = blockIdx.y, r0 = blockIdx.x * 8, h = threadIdx.x;
    __shared__ float sa[8 * 200];
    for (int idx = h; idx < 1600; idx += 256)
        sa[idx] = An[(size_t)(t * 200 + r0) * 200 + idx];
    __syncthreads();
    const float* Xt = X + (size_t)t * 200 * 256;
    float acc[8];
#pragma unroll
    for (int m = 0; m < 8; ++m) acc[m] = 0.f;
    for (int s = 0; s < 200; ++s) {
        float xv = Xt[s * 256 + h];
#pragma unroll
        for (int m = 0; m < 8; ++m) acc[m] += sa[m * 200 + s] * xv;
    }
    float bb = b[h];
#pragma unroll
    for (int m = 0; m < 8; ++m)
        out[(size_t)(t * 200 + r0 + m) * 256 + h] = fmaxf(acc[m] + bb, 0.f);
}

// ---------------- K13: mean over R ----------------
__global__ __launch_bounds__(256) void gemb_kernel(const float* __restrict__ g2,
                                                   float* __restrict__ g_emb) {
    int t = blockIdx.x, h = threadIdx.x;
    float acc = 0.f;
    for (int r = 0; r < 200; ++r) acc += g2[(size_t)(t * 200 + r) * 256 + h];
    g_emb[t * 256 + h] = acc * (1.f / 200.f);
}

// ---------------- K14: transpose 768x256 -> [k][j] ----------------
__global__ __launch_bounds__(256) void transpose_768x256_kernel(const float* __restrict__ in,
                                                                float* __restrict__ outT) {
    int gid = blockIdx.x * 256 + threadIdx.x;
    int k = gid / 768, j = gid % 768;
    outT[gid] = in[j * 256 + k];
}

// ---------------- K15: GRU input-side matvecs ----------------
__global__ __launch_bounds__(768) void gi_kernel(const float* __restrict__ g_emb,
                                                 const float* __restrict__ wihT,
                                                 const float* __restrict__ bih,
                                                 float* __restrict__ GI) {
    int t = blockIdx.x, j = threadIdx.x;
    __shared__ float sg[256];
    if (j < 256) sg[j] = g_emb[t * 256 + j];
    __syncthreads();
    float acc = bih[j];
    for (int k = 0; k < 256; ++k) acc += sg[k] * wihT[k * 768 + j];
    GI[t * 768 + j] = acc;
}

// ---------------- K16: GRU with register-resident weights, 6 blocks, flag sync ----------------
__global__ __launch_bounds__(256) void gru_cls_kernel(const float* __restrict__ GI,
                                                      const float* __restrict__ whhT,
                                                      const float* __restrict__ bhh,
                                                      const float* __restrict__ cls_w,
                                                      const float* __restrict__ cls_b,
                                                      float* __restrict__ GH,
                                                      int* __restrict__ flags,
                                                      float* __restrict__ out) {
    int b = blockIdx.x, tid = threadIdx.x;
    int jl = tid & 127;               // local j
    int kc = tid >> 7;                // k-chunk 0/1
    int j = b * 128 + jl;             // global output row 0..767
    float wreg[128];
#pragma unroll 16
    for (int k = 0; k < 128; ++k)
        wreg[k] = whhT[(size_t)(kc * 128 + k) * 768 + j];
    __shared__ float hcur[256];
    __shared__ float part[256];
    __shared__ float s0[4], s1[4];
    hcur[tid] = 0.f;
    __syncthreads();
    for (int st = 0; st < 16; ++st) {
        float p = 0.f;
        const float* hb = &hcur[kc * 128];
#pragma unroll 16
        for (int k = 0; k < 128; ++k) p += hb[k] * wreg[k];
        part[tid] = p;
        __syncthreads();
        if (tid < 128) {
            GH[st * 768 + b * 128 + tid] = part[tid] + part[tid + 128];
        }
        __threadfence();
        __syncthreads();
        if (tid == 0)
            __hip_atomic_store(&flags[b], st + 1, __ATOMIC_RELEASE, __HIP_MEMORY_SCOPE_AGENT);
        // wait for all blocks' slices of this step
        for (int bb = 0; bb < GRU_BLOCKS; ++bb) {
            while (__hip_atomic_load(&flags[bb], __ATOMIC_ACQUIRE, __HIP_MEMORY_SCOPE_AGENT) <= st)
                __builtin_amdgcn_s_sleep(2);
        }
        // every block computes h redundantly
        float ghr = GH[st * 768 + tid]       + bhh[tid];
        float ghz = GH[st * 768 + 256 + tid] + bhh[256 + tid];
        float ghn = GH[st * 768 + 512 + tid] + bhh[512 + tid];
        float gir = GI[st * 768 + tid];
        float giz = GI[st * 768 + 256 + tid];
        float gin = GI[st * 768 + 512 + tid];
        float r = 1.f / (1.f + expf(-(gir + ghr)));
        float z = 1.f / (1.f + expf(-(giz + ghz)));
        float nn = tanhf(gin + r * ghn);
        float hnew = (1.f - z) * nn + z * hcur[tid];
        __syncthreads();
        hcur[tid] = hnew;
        __syncthreads();
    }
    if (b == 0) {
        float v0 = hcur[tid] * cls_w[tid];
        float v1 = hcur[tid] * cls_w[256 + tid];
        waveReduce2(v0, v1);
        int lane = tid & 63, wid = tid >> 6;
        if (lane == 0) { s0[wid] = v0; s1[wid] = v1; }
        __syncthreads();
        if (tid == 0) {
            out[0] = s0[0] + s0[1] + s0[2] + s0[3] + cls_b[0];
            out[1] = s1[0] + s1[1] + s1[2] + s1[3] + cls_b[1];
        }
    }
}

// ---------------- K17: avg_adj + edge variance ----------------
__global__ __launch_bounds__(256) void edge_kernel(const float* __restrict__ adj,
                                                   float* __restrict__ out) {
    int gid = blockIdx.x * 256 + threadIdx.x;
    float var = 0.f;
    if (gid < 40000) {
        float v[16]; float s = 0.f;
#pragma unroll
        for (int t = 0; t < 16; ++t) { v[t] = adj[t * 40000 + gid]; s += v[t]; }
        float mean = s * (1.f / 16.f);
        float q = 0.f;
#pragma unroll
        for (int t = 0; t < 16; ++t) { float d = v[t] - mean; q += d * d; }
        var = q * (1.f / 15.f);
        out[2 + gid] = mean;
    }
    float dummy = 0.f;
    waveReduce2(var, dummy);
    __shared__ float sa[4];
    int lane = threadIdx.x & 63, wid = threadIdx.x >> 6;
    if (lane == 0) sa[wid] = var;
    __syncthreads();
    if (threadIdx.x == 0) {
        float bs = sa[0] + sa[1] + sa[2] + sa[3];
        atomicAdd(&out[40002], bs * (1.f / 40000.f));
    }
}

// ---------------- host ----------------
extern "C" void kernel_launch(void* const* d_in, const int* in_sizes, int n_in,
                              void* d_out, int out_size, void* d_ws, size_t ws_size,
                              hipStream_t stream) {
    const float* tw      = (const float*)d_in[0];
    const float* wav_r   = (const float*)d_in[1];
    const float* wav_i   = (const float*)d_in[2];
    const float* conv1_w = (const float*)d_in[3];
    const float* conv1_b = (const float*)d_in[4];
    const float* bn1_g   = (const float*)d_in[5];
    const float* bn1_b   = (const float*)d_in[6];
    const float* conv2_w = (const float*)d_in[7];
    const float* conv2_b = (const float*)d_in[8];
    const float* bn2_g   = (const float*)d_in[9];
    const float* bn2_b   = (const float*)d_in[10];
    const float* fc_w    = (const float*)d_in[11];
    const float* fc_b    = (const float*)d_in[12];
    const float* q_w     = (const float*)d_in[13];
    const float* q_b     = (const float*)d_in[14];
    const float* k_w     = (const float*)d_in[15];
    const float* k_b     = (const float*)d_in[16];
    const float* gcn1_w  = (const float*)d_in[17];
    const float* gcn1_b  = (const float*)d_in[18];
    const float* gcn2_w  = (const float*)d_in[19];
    const float* gcn2_b  = (const float*)d_in[20];
    const float* gru_wih = (const float*)d_in[21];
    const float* gru_whh = (const float*)d_in[22];
    const float* gru_bih = (const float*)d_in[23];
    const float* gru_bhh = (const float*)d_in[24];
    const float* cls_w   = (const float*)d_in[25];
    const float* cls_b   = (const float*)d_in[26];
    float* out = (float*)d_out;
    (void)in_sizes; (void)n_in; (void)out_size;

    const size_t POOLED1_B = (size_t)N_ * 16 * 16 * 25 * 4;     // 81.92 MB
    const size_t SCALU_B   = (size_t)N_ * 1600 * 4;             // 20.48 MB
    const size_t MM_FULL_B = (size_t)N_ * 96 * 64 * 4;          // 78.64 MB
    const size_t MM_MAX_B  = (size_t)N_ * 96 * 32 * 4;          // 39.32 MB
    const size_t P1S_B     = (size_t)N_ * 16 * 8;
    const size_t P2S_B     = (size_t)N_ * 32 * 8;
    const size_t WT_B      = (size_t)768 * 256 * 4;
    size_t fixed = POOLED1_B + SCALU_B + 2 * P1S_B + 2 * P2S_B + 2 * WT_B + 8 * 256 + 65536;
    int store_min = (ws_size >= fixed + MM_FULL_B) ? 1 : 0;
    const size_t MM_B = store_min ? MM_FULL_B : MM_MAX_B;

    size_t off = 0;
    char* Wb = (char*)d_ws;
    auto take = [&](size_t bytes) -> char* {
        char* p = Wb + off;
        off += (bytes + 255) & ~(size_t)255;
        return p;
    };
    float* pooled1 = (float*)take(POOLED1_B);
    char*  scalU   = take(SCALU_B);
    char*  mmU     = take(MM_B);
    double* p1sum = (double*)take(P1S_B);
    double* p1sq  = (double*)take(P1S_B);
    double* p2sum = (double*)take(P2S_B);
    double* p2sq  = (double*)take(P2S_B);
    float* scale1 = (float*)take(64 * 4);
    float* shift1 = (float*)take(64 * 4);
    float* scale2 = (float*)take(64 * 4);
    float* shift2 = (float*)take(64 * 4);
    float* wihT   = (float*)take(WT_B);
    float* whhT   = (float*)take(WT_B);
    float* dinv   = (float*)take((size_t)T_ * 200 * 4);
    float* GH     = (float*)take((size_t)16 * 768 * 4);
    int*   flags  = (int*)take(256);

    // scalU region: scal until conv1_norm_pool; then pm/emb/Q/Kp
    float* scal = (float*)scalU;
    float* pm   = (float*)(scalU + 0);
    float* emb  = (float*)(scalU + 409600);
    float* Q    = (float*)(scalU + 409600 + 1638400);
    float* Kp   = (float*)(scalU + 409600 + 2 * 1638400);

    // mmU region: mm until pool_mean; then attn/adj/An/X1/g1/X2/g2/g_emb/GI
    float* mm   = (float*)mmU;
    size_t moff = 0;
    auto mtake = [&](size_t bytes) -> float* {
        float* p = (float*)(mmU + moff);
        moff += (bytes + 255) & ~(size_t)255;
        return p;
    };
    float* attn  = mtake((size_t)T_ * 200 * 200 * 4);
    float* adj   = mtake((size_t)T_ * 200 * 200 * 4);
    float* An    = mtake((size_t)T_ * 200 * 200 * 4);
    float* X1    = mtake((size_t)N_ * 256 * 4);
    float* g1    = mtake((size_t)N_ * 256 * 4);
    float* X2    = mtake((size_t)N_ * 256 * 4);
    float* g2    = mtake((size_t)N_ * 256 * 4);
    float* g_emb = mtake((size_t)T_ * 256 * 4);
    float* GI    = mtake((size_t)T_ * 768 * 4);

    // 0) weight transposes
    transpose_768x256_kernel<<<768, 256, 0, stream>>>(gru_wih, wihT);
    transpose_768x256_kernel<<<768, 256, 0, stream>>>(gru_whh, whhT);
    // 1) CWT + conv1 stats -> BN1 -> norm+pool
    cwt_conv1_stats_kernel<<<N_, 256, 0, stream>>>(tw, wav_r, wav_i, conv1_w, conv1_b,
                                                   scal, p1sum, p1sq);
    bn_finalize_kernel<<<16, 256, 0, stream>>>(p1sum, p1sq, bn1_g, bn1_b, scale1, shift1,
                                               16, 1.0 / 5120000.0);
    conv1_norm_pool_kernel<<<N_, 256, 0, stream>>>(scal, conv1_w, conv1_b, scale1, shift1,
                                                   pooled1);
    // 2) conv2 single pass -> BN2 -> pooled mean
    conv2_compute_kernel<<<N_, 256, 0, stream>>>(pooled1, conv2_w, conv2_b, mm,
                                                 p2sum, p2sq, store_min);
    bn_finalize_kernel<<<32, 256, 0, stream>>>(p2sum, p2sq, bn2_g, bn2_b, scale2, shift2,
                                               32, 1.0 / 1280000.0);
    pool_mean_kernel<<<N_, 256, 0, stream>>>(mm, scale2, shift2, pm, store_min);
    // 3) FC + Q/K
    fc_kernel<<<N_, 128, 0, stream>>>(pm, fc_w, fc_b, emb);
    qk_kernel<<<dim3(N_, 2), 128, 0, stream>>>(emb, q_w, q_b, k_w, k_b, Q, Kp);
    // 4) attention -> topk softmax -> An
    attn_kernel<<<dim3(200, 16), 256, 0, stream>>>(Q, Kp, attn);
    topk_softmax_kernel<<<N_, 64, 0, stream>>>(attn, adj);
    deg_kernel<<<16, 256, 0, stream>>>(adj, dinv);
    an_tile_kernel<<<dim3(16, 16), 256, 0, stream>>>(adj, dinv, An);
    // 5) GCN x2
    linear8_kernel<<<N_ / 8, 256, 0, stream>>>(emb, gcn1_w, X1, 128);
    gcn_agg_kernel<<<dim3(25, 16), 256, 0, stream>>>(An, X1, gcn1_b, g1);
    linear8_kernel<<<N_ / 8, 256, 0, stream>>>(g1, gcn2_w, X2, 256);
    gcn_agg_kernel<<<dim3(25, 16), 256, 0, stream>>>(An, X2, gcn2_b, g2);
    // 6) graph embedding + GRU + classifier
    gemb_kernel<<<16, 256, 0, stream>>>(g2, g_emb);
    gi_kernel<<<16, 768, 0, stream>>>(g_emb, wihT, gru_bih, GI);
    hipMemsetAsync(flags, 0, 256, stream);
    gru_cls_kernel<<<GRU_BLOCKS, 256, 0, stream>>>(GI, whhT, gru_bhh, cls_w, cls_b,
                                                   GH, flags, out);
    // 7) avg_adj + edge_var
    hipMemsetAsync(out + 40002, 0, sizeof(float), stream);
    edge_kernel<<<(40000 + 255) / 256, 256, 0, stream>>>(adj, out);
}